// Round 2
// 12439.834 us; speedup vs baseline: 1.2668x; 1.2668x over previous
//
#include <hip/hip_runtime.h>

typedef unsigned short u16;
typedef unsigned int   u32;
typedef unsigned char  u8;

constexpr int kB = 32, kT = 128, kS = 256, kE = 512, kH = 1024, kG = 4096;

__device__ __forceinline__ float b2f(u16 v){ return __uint_as_float(((u32)v) << 16); }
__device__ __forceinline__ u16  f2b(float f){
    u32 u = __float_as_uint(f);
    return (u16)((u + 0x7FFFu + ((u >> 16) & 1u)) >> 16);
}
__device__ __forceinline__ float sigf(float x){ return 1.f / (1.f + expf(-x)); }
// dt==0: buffer is bf16 (u16); dt==1: buffer is fp32 (validated: fp32 on this harness)
__device__ __forceinline__ float ldin(const void* p, size_t i, int dt){
    return dt ? ((const float*)p)[i] : b2f(((const u16*)p)[i]);
}

// ---------------- input dtype detection (bf16 vs fp32) ----------------
__global__ void detect_dtype_k(const void* __restrict__ inputs, int* __restrict__ dtflag)
{
    __shared__ int bad;
    int t = threadIdx.x;
    if (t == 0) bad = 0;
    __syncthreads();
    const u16* p = (const u16*)inputs;
    int l = 0;
    for (int i = t; i < 4096; i += 256){
        u16 v = p[i];
        int e = (v >> 7) & 0xFF;
        if (v != 0 && (e < 90 || e > 140)) l = 1;
    }
    if (l) atomicOr(&bad, 1);
    __syncthreads();
    if (t == 0) *dtflag = bad;   // 1 = fp32, 0 = bf16
}

// ---------------- mask detection -> maskflag[b][s] = 1.0 (pad) / 0.0 ----------------
__global__ void prep_mask_k(const void* __restrict__ mask, float* __restrict__ maskflag)
{
    __shared__ int bad32, bad16, bad8, evenNZ;
    int t = threadIdx.x;
    if (t == 0){ bad32 = 0; bad16 = 0; bad8 = 0; evenNZ = 0; }
    __syncthreads();
    const u32* w32 = (const u32*)mask;
    const u16* w16 = (const u16*)mask;
    const u8*  w8  = (const u8*)mask;
    int l32 = 0, l16 = 0, l8 = 0, lev = 0;
    for (int i = t; i < 2048; i += 256){ u32 v = w32[i]; l32 |= (v > 1u); }
    for (int i = t; i < 4096; i += 256){
        u16 v = w16[i];
        l16 |= (v != 0 && v != 0x3F80u);
        if ((i & 1) == 0 && v != 0) lev = 1;
    }
    for (int i = t; i < 8192; i += 256){ l8 |= (w8[i] > 1); }
    if (l32) atomicOr(&bad32, 1);
    if (l16) atomicOr(&bad16, 1);
    if (l8)  atomicOr(&bad8, 1);
    if (lev) atomicOr(&evenNZ, 1);
    __syncthreads();
    int mode;                       // 0=int32, 1=bf16, 2=uint8, 3=fp32
    if (!bad32)       mode = 0;
    else if (!bad16)  mode = evenNZ ? 1 : 3;
    else if (!bad8)   mode = 2;
    else              mode = 3;
    for (int i = t; i < kB * kS; i += 256){
        bool m;
        if (mode == 0)      m = (((const int*)mask)[i] != 0);
        else if (mode == 1) m = (w16[i] != 0);
        else if (mode == 2) m = (w8[i] != 0);
        else                m = (((const float*)mask)[i] != 0.f);
        maskflag[i] = m ? 1.f : 0.f;
    }
}

// ---------------- bias / fold-vector precompute ----------------
__global__ void prep_bias_k(const void* __restrict__ Wq, const void* __restrict__ bq,
                            const void* __restrict__ Wk, const void* __restrict__ bk,
                            const void* __restrict__ bv, const void* __restrict__ Wo,
                            const void* __restrict__ bo,
                            const void* __restrict__ bih0, const void* __restrict__ bhh0,
                            const void* __restrict__ bih1, const void* __restrict__ bhh1,
                            float* __restrict__ bkq, float* __restrict__ bvo,
                            float* __restrict__ ubq, float* __restrict__ bof,
                            float* __restrict__ bias01, float* __restrict__ bias1,
                            float* __restrict__ cbqbk, const int* __restrict__ dtflag)
{
    int dt = *dtflag;
    int idx = blockIdx.x * 256 + threadIdx.x;
    if (idx < 1024){
        float s = 0.f;
        for (int i = 0; i < 1024; i++) s += ldin(bk, i, dt) * ldin(Wq, (size_t)i * 1024 + idx, dt);
        bkq[idx] = s;
    } else if (idx < 2048){ int o2 = idx - 1024;
        float s = 0.f;
        for (int h = 0; h < 1024; h++) s += ldin(bv, h, dt) * ldin(Wo, (size_t)o2 * 1024 + h, dt);
        bvo[o2] = s;
    } else if (idx < 3072){ int e = idx - 2048;
        float s = 0.f;
        for (int i = 0; i < 1024; i++) s += ldin(bq, i, dt) * ldin(Wk, (size_t)i * 1024 + e, dt);
        ubq[e] = s;
    } else if (idx < 4096){ int o2 = idx - 3072;
        bof[o2] = ldin(bo, o2, dt);
    } else if (idx < 8192){ int j = idx - 4096;
        bias01[j] = ldin(bih0, j, dt) + ldin(bhh0, j, dt);
    } else if (idx < 12288){ int j = idx - 8192;
        bias1[j] = ldin(bih1, j, dt) + ldin(bhh1, j, dt);
    } else if (idx == 12288){
        float s = 0.f;
        for (int i = 0; i < 1024; i++) s += ldin(bq, i, dt) * ldin(bk, i, dt);
        cbqbk[0] = s;
    }
}

// ---------------- inputs -> fp32 copy, same [B,T,E] layout ----------------
__global__ void copy_inputs_k(const void* __restrict__ inputs, float* __restrict__ xf,
                              const int* __restrict__ dtflag)
{
    int dt = *dtflag;
    int idx = blockIdx.x * 256 + threadIdx.x;   // grid 8192 -> 2097152
    xf[idx] = ldin(inputs, idx, dt);
}

// ---------------- initial states ----------------
__global__ void init_state_k(const void* __restrict__ enc_c, float* __restrict__ h0,
                             float* __restrict__ c0, float* __restrict__ h1,
                             float* __restrict__ c1, const int* __restrict__ dtflag)
{
    int dt = *dtflag;
    int idx = blockIdx.x * 256 + threadIdx.x;     // 32768
    int b = idx >> 10, h = idx & 1023;
    float cv = (h < 512) ? ldin(enc_c, (size_t)b * 512 + h, dt)
                         : ldin(enc_c, (size_t)(32 + b) * 512 + (h - 512), dt);
    h0[idx] = 0.f; h1[idx] = 0.f; c0[idx] = cv; c1[idx] = cv;
}

// ---------------- transpose to bf16: WT[e*ldt + j] = bf16(W[j*ldw + col_off + e]) ----------------
__global__ void transpose_b_k(const void* __restrict__ W, int ldw, int col_off,
                              u16* __restrict__ WT, int ldt, const int* __restrict__ dtflag)
{
    __shared__ float tile[64][65];
    int dt = *dtflag;
    int j0 = blockIdx.x * 64, e0 = blockIdx.y * 64;
    for (int i = 0; i < 16; i++){
        int idx = threadIdx.x + i * 256;
        int jr = idx >> 6, ec = idx & 63;
        tile[jr][ec] = ldin(W, (size_t)(j0 + jr) * ldw + col_off + e0 + ec, dt);
    }
    __syncthreads();
    for (int i = 0; i < 16; i++){
        int idx = threadIdx.x + i * 256;
        int er = idx >> 6, jc = idx & 63;
        WT[(size_t)(e0 + er) * ldt + j0 + jc] = f2b(tile[jc][er]);
    }
}

// ---------------- weight-weight fold GEMM: Out[e][c] = sum_k A[k][e] * B(k,c) ----------------
template<int BMODE>
__global__ __launch_bounds__(256) void gemm_ww_k(
    const void* __restrict__ A, const void* __restrict__ Bm,
    float* __restrict__ Out, const int* __restrict__ dtflag)
{
    __shared__ float As[32][68];
    __shared__ float Bs[32][68];
    const int dt = *dtflag;
    const int tid = threadIdx.x;
    const int tile_r = blockIdx.x * 64, tile_c = blockIdx.y * 64;
    const int r0 = (tid & 15) * 4, c0 = (tid >> 4) * 4;
    float acc[16];
    #pragma unroll
    for (int i = 0; i < 16; i++) acc[i] = 0.f;
    for (int k0 = 0; k0 < 1024; k0 += 32){
        int rr = tid & 63, kq = tid >> 6;
        #pragma unroll
        for (int i = 0; i < 8; i++){
            int k = kq * 8 + i;
            As[k][rr] = ldin(A, (size_t)(k0 + k) * 1024 + tile_r + rr, dt);
        }
        #pragma unroll
        for (int i = 0; i < 8; i++){
            int k = kq * 8 + i;
            size_t addr = (BMODE == 0) ? (size_t)(k0 + k) * 1024 + tile_c + rr
                                       : (size_t)(tile_c + rr) * 1024 + k0 + k;
            Bs[k][rr] = ldin(Bm, addr, dt);
        }
        __syncthreads();
        #pragma unroll
        for (int k = 0; k < 32; k++){
            float4 av = *(const float4*)&As[k][r0];
            float4 bv = *(const float4*)&Bs[k][c0];
            acc[0]  += av.x * bv.x; acc[1]  += av.x * bv.y; acc[2]  += av.x * bv.z; acc[3]  += av.x * bv.w;
            acc[4]  += av.y * bv.x; acc[5]  += av.y * bv.y; acc[6]  += av.y * bv.z; acc[7]  += av.y * bv.w;
            acc[8]  += av.z * bv.x; acc[9]  += av.z * bv.y; acc[10] += av.z * bv.z; acc[11] += av.z * bv.w;
            acc[12] += av.w * bv.x; acc[13] += av.w * bv.y; acc[14] += av.w * bv.z; acc[15] += av.w * bv.w;
        }
        __syncthreads();
    }
    #pragma unroll
    for (int i = 0; i < 4; i++){
        int gr = tile_r + r0 + i;
        #pragma unroll
        for (int jj = 0; jj < 4; jj++)
            Out[(size_t)gr * 1024 + tile_c + c0 + jj] = acc[i * 4 + jj];
    }
}

// ---------------- enc-side fold GEMM: bf16 out, row remap (s*32+b) -> [b][s] ----------------
__global__ __launch_bounds__(256) void gemm_enc_k(
    const void* __restrict__ A, const float* __restrict__ Bw,
    u16* __restrict__ Outb, const float* __restrict__ bias, float scale,
    const int* __restrict__ dtflag)
{
    __shared__ float As[32][68];
    __shared__ float Bs[32][68];
    const int dt = *dtflag;
    const int tid = threadIdx.x;
    const int tile_r = blockIdx.x * 64, tile_c = blockIdx.y * 64;
    const int r0 = (tid & 15) * 4, c0 = (tid >> 4) * 4;
    float acc[16];
    #pragma unroll
    for (int i = 0; i < 16; i++) acc[i] = 0.f;
    for (int k0 = 0; k0 < 1024; k0 += 32){
        int rr = tid & 63, kq = tid >> 6;
        size_t base = (size_t)(tile_r + rr) * 1024 + k0 + kq * 8;
        #pragma unroll
        for (int i = 0; i < 8; i++) As[kq * 8 + i][rr] = ldin(A, base + i, dt);
        #pragma unroll
        for (int i = 0; i < 8; i++){
            int k = kq * 8 + i;
            Bs[k][rr] = Bw[(size_t)(k0 + k) * 1024 + tile_c + rr];
        }
        __syncthreads();
        #pragma unroll
        for (int k = 0; k < 32; k++){
            float4 av = *(const float4*)&As[k][r0];
            float4 bv = *(const float4*)&Bs[k][c0];
            acc[0]  += av.x * bv.x; acc[1]  += av.x * bv.y; acc[2]  += av.x * bv.z; acc[3]  += av.x * bv.w;
            acc[4]  += av.y * bv.x; acc[5]  += av.y * bv.y; acc[6]  += av.y * bv.z; acc[7]  += av.y * bv.w;
            acc[8]  += av.z * bv.x; acc[9]  += av.z * bv.y; acc[10] += av.z * bv.z; acc[11] += av.z * bv.w;
            acc[12] += av.w * bv.x; acc[13] += av.w * bv.y; acc[14] += av.w * bv.z; acc[15] += av.w * bv.w;
        }
        __syncthreads();
    }
    #pragma unroll
    for (int i = 0; i < 4; i++){
        int gr = tile_r + r0 + i;
        int b = gr & 31, s = gr >> 5;
        #pragma unroll
        for (int jj = 0; jj < 4; jj++){
            int gc = tile_c + c0 + jj;
            Outb[(((size_t)((b << 8) | s)) << 10) + gc] = f2b((acc[i * 4 + jj] + bias[gc]) * scale);
        }
    }
}

// ---------------- skbqs[b][s] = (bq.K[s,b,:]) * scale ----------------
__global__ __launch_bounds__(256) void skbq_k(
    const void* __restrict__ enc, const float* __restrict__ ubq,
    const float* __restrict__ cbqbk, float* __restrict__ skbqs,
    const int* __restrict__ dtflag)
{
    int dt = *dtflag;
    int w = (blockIdx.x * 256 + threadIdx.x) >> 6;   // 0..8191 = s*32+b
    int lane = threadIdx.x & 63;
    int s = w >> 5, b = w & 31;
    size_t base = (size_t)w * 1024 + lane * 16;
    float acc = 0.f;
    #pragma unroll
    for (int i = 0; i < 16; i++) acc += ubq[lane * 16 + i] * ldin(enc, base + i, dt);
    #pragma unroll
    for (int off = 32; off; off >>= 1) acc += __shfl_down(acc, off, 64);
    if (lane == 0) skbqs[b * 256 + s] = (acc + cbqbk[0]) * 0.03125f;
}

// ---------------- prologue scores: psc[0][b][s] = c1.KQb full dot; psc[1..3]=0 ----------------
__global__ __launch_bounds__(256) void scores0_k(
    const float* __restrict__ c1f, const u16* __restrict__ KQb, float* __restrict__ psc)
{
    int w = (blockIdx.x * 256 + threadIdx.x) >> 6;    // 0..8191
    int lane = threadIdx.x & 63;
    int b = w >> 8, s = w & 255;
    const u16*  kr = KQb + (((size_t)((b << 8) | s)) << 10) + lane * 16;
    const float* cr = c1f + ((size_t)b << 10) + lane * 16;
    float cb[16];
    *(float4*)&cb[0]  = *(const float4*)(cr);
    *(float4*)&cb[4]  = *(const float4*)(cr + 4);
    *(float4*)&cb[8]  = *(const float4*)(cr + 8);
    *(float4*)&cb[12] = *(const float4*)(cr + 12);
    u32 kb[8];
    *(uint4*)&kb[0] = *(const uint4*)(kr);
    *(uint4*)&kb[4] = *(const uint4*)(kr + 8);
    float acc = 0.f;
    #pragma unroll
    for (int i = 0; i < 8; i++){
        acc += cb[2 * i]     * b2f((u16)(kb[i] & 0xFFFFu));
        acc += cb[2 * i + 1] * b2f((u16)(kb[i] >> 16));
    }
    #pragma unroll
    for (int off = 32; off; off >>= 1) acc += __shfl_down(acc, off, 64);
    if (lane == 0){
        psc[((0 * 32 + b) << 8) + s] = acc;
        psc[((1 * 32 + b) << 8) + s] = 0.f;
        psc[((2 * 32 + b) << 8) + s] = 0.f;
        psc[((3 * 32 + b) << 8) + s] = 0.f;
    }
}

// ---------------- per-step: softmax over psc-sum + ctx = attn@Vob + bo ----------------
// grid 256 = (b<<3 | ht), ht covers 128 h each (2 h per lane via u32 loads)
__global__ __launch_bounds__(256) void cv_k(
    const float* __restrict__ psc, const float* __restrict__ skbqs,
    const float* __restrict__ maskflag, const u16* __restrict__ Vob,
    const float* __restrict__ bof, float* __restrict__ ctx)
{
    __shared__ float attn[256];
    __shared__ float wred[8];
    __shared__ float2 part[4][64];
    int b = blockIdx.x >> 3, ht = blockIdx.x & 7;
    int tid = threadIdx.x;
    int is = (b << 8) + tid;
    float scv;
    if (maskflag[is] != 0.f) scv = -1e9f;
    else scv = psc[((0 * 32 + b) << 8) + tid] + psc[((1 * 32 + b) << 8) + tid]
             + psc[((2 * 32 + b) << 8) + tid] + psc[((3 * 32 + b) << 8) + tid]
             + skbqs[is];
    float m = scv;
    #pragma unroll
    for (int off = 32; off; off >>= 1) m = fmaxf(m, __shfl_down(m, off, 64));
    if ((tid & 63) == 0) wred[tid >> 6] = m;
    __syncthreads();
    float mm = fmaxf(fmaxf(wred[0], wred[1]), fmaxf(wred[2], wred[3]));
    float ex = expf(scv - mm);
    float ssum = ex;
    #pragma unroll
    for (int off = 32; off; off >>= 1) ssum += __shfl_down(ssum, off, 64);
    if ((tid & 63) == 0) wred[4 + (tid >> 6)] = ssum;
    __syncthreads();
    float tot = (wred[4] + wred[5]) + (wred[6] + wred[7]);
    attn[tid] = ex / tot;
    __syncthreads();
    int hl = tid & 63, scn = tid >> 6;
    int h2 = ht * 128 + hl * 2;
    const u16* vcol = Vob + ((size_t)b << 18) + h2;
    float a0 = 0.f, a1 = 0.f;
    #pragma unroll 8
    for (int s = scn; s < 256; s += 4){
        u32 v = *(const u32*)(vcol + ((size_t)s << 10));
        float at = attn[s];
        a0 += at * b2f((u16)(v & 0xFFFFu));
        a1 += at * b2f((u16)(v >> 16));
    }
    part[scn][hl] = make_float2(a0, a1);
    __syncthreads();
    if (tid < 64){
        float2 p0 = part[0][tid], p1 = part[1][tid], p2 = part[2][tid], p3 = part[3][tid];
        int h = ht * 128 + tid * 2;
        ctx[(b << 10) + h]     = p0.x + p1.x + p2.x + p3.x + bof[h];
        ctx[(b << 10) + h + 1] = p0.y + p1.y + p2.y + p3.y + bof[h + 1];
    }
}

// ---------------- FALLBACK layer-0 gates split-K: x_t, ctx, h0 (20 slices) ----------------
__global__ __launch_bounds__(256) void gates0_k(
    const u16* __restrict__ WTx, const u16* __restrict__ WTc, const u16* __restrict__ WTh,
    const float* __restrict__ xt, const float* __restrict__ ctx, const float* __restrict__ h0,
    float* __restrict__ partial)
{
    int jt = blockIdx.x, es = blockIdx.y;
    int j = jt * 256 + threadIdx.x;
    const u16* WT; const float* act; int e0, bstride;
    if (es < 4)       { WT = WTx; act = xt;  e0 = es * 128;        bstride = kT * kE; }
    else if (es < 12) { WT = WTc; act = ctx; e0 = (es - 4) * 128;  bstride = 1024; }
    else              { WT = WTh; act = h0;  e0 = (es - 12) * 128; bstride = 1024; }
    float acc[32];
    #pragma unroll
    for (int b = 0; b < 32; b++) acc[b] = 0.f;
    #pragma unroll
    for (int ec = 0; ec < 2; ec++){
        float w[64];
        const u16* wp = WT + (size_t)(e0 + ec * 64) * kG + j;
        #pragma unroll
        for (int k = 0; k < 64; k++) w[k] = b2f(wp[(size_t)k * kG]);
        const float* ap = act + e0 + ec * 64;
        #pragma unroll 4
        for (int b = 0; b < 32; b++){
            const float* ab = ap + (size_t)b * bstride;
            float s0 = 0.f, s1 = 0.f;
            #pragma unroll
            for (int k = 0; k < 64; k += 2){ s0 += w[k] * ab[k]; s1 += w[k + 1] * ab[k + 1]; }
            acc[b] += s0 + s1;
        }
    }
    float* po = partial + (size_t)(es * 32) * kG + j;
    #pragma unroll 4
    for (int b = 0; b < 32; b++) po[(size_t)b * kG] = acc[b];
}

// ---------------- generic 2-input gates split-K (16 slices): actA (8), actB (8) ----------------
__global__ __launch_bounds__(256) void gates1_k(
    const u16* __restrict__ WTa, const u16* __restrict__ WTb,
    const float* __restrict__ actA, const float* __restrict__ actB,
    float* __restrict__ partial)
{
    int jt = blockIdx.x, es = blockIdx.y;
    int j = jt * 256 + threadIdx.x;
    const u16* WT    = (es < 8) ? WTa  : WTb;
    const float* act = (es < 8) ? actA : actB;
    int e0 = (es & 7) * 128;
    float acc[32];
    #pragma unroll
    for (int b = 0; b < 32; b++) acc[b] = 0.f;
    #pragma unroll
    for (int ec = 0; ec < 2; ec++){
        float w[64];
        const u16* wp = WT + (size_t)(e0 + ec * 64) * kG + j;
        #pragma unroll
        for (int k = 0; k < 64; k++) w[k] = b2f(wp[(size_t)k * kG]);
        const float* ap = act + e0 + ec * 64;
        #pragma unroll 4
        for (int b = 0; b < 32; b++){
            const float* ab = ap + (b << 10);
            float s0 = 0.f, s1 = 0.f;
            #pragma unroll
            for (int k = 0; k < 64; k += 2){ s0 += w[k] * ab[k]; s1 += w[k + 1] * ab[k + 1]; }
            acc[b] += s0 + s1;
        }
    }
    float* po = partial + (size_t)(es * 32) * kG + j;
    #pragma unroll 4
    for (int b = 0; b < 32; b++) po[(size_t)b * kG] = acc[b];
}

// ---------------- one-time: xw[t][b][j] = x[b,t,:] @ Wih0x^T  (hoists x-slices out of loop) ----------------
__global__ __launch_bounds__(256) void xw_k(
    const u16* __restrict__ WTx, const float* __restrict__ xf, float* __restrict__ xw)
{
    int jt = blockIdx.x, t = blockIdx.y;
    int j = jt * 256 + threadIdx.x;
    float acc[32];
    #pragma unroll
    for (int b = 0; b < 32; b++) acc[b] = 0.f;
    for (int ec = 0; ec < 8; ec++){
        float w[64];
        const u16* wp = WTx + (size_t)(ec * 64) * kG + j;
        #pragma unroll
        for (int k = 0; k < 64; k++) w[k] = b2f(wp[(size_t)k * kG]);
        #pragma unroll 4
        for (int b = 0; b < 32; b++){
            const float* ab = xf + ((size_t)b * kT + t) * kE + ec * 64;
            float s0 = 0.f, s1 = 0.f;
            #pragma unroll
            for (int k = 0; k < 64; k += 2){ s0 += w[k] * ab[k]; s1 += w[k + 1] * ab[k + 1]; }
            acc[b] += s0 + s1;
        }
    }
    float* po = xw + ((size_t)t * 32) * kG + j;
    #pragma unroll 4
    for (int b = 0; b < 32; b++) po[(size_t)b * kG] = acc[b];
}

// ---------------- LSTM cell (layer 0): unrolled compile-time reduction ----------------
template<int NSL, bool XW>
__global__ __launch_bounds__(256) void cell_k(
    const float* __restrict__ partial, const float* __restrict__ biasv,
    const float* __restrict__ xwrow,
    const float* __restrict__ c_prev, float* __restrict__ c_out,
    float* __restrict__ h_out)
{
    int idx = blockIdx.x * 256 + threadIdx.x;     // 32768
    int b = idx >> 10, h = idx & 1023;
    float g[4];
    #pragma unroll
    for (int gi = 0; gi < 4; gi++){
        int j = (gi << 10) + h;
        float s = biasv[j];
        if (XW) s += xwrow[(b << 12) + j];
        const float* pp = partial + (size_t)b * kG + j;
        #pragma unroll
        for (int es = 0; es < NSL; es++) s += pp[(size_t)es * 32 * kG];
        g[gi] = s;
    }
    float gi_ = sigf(g[0]);
    float gf_ = sigf(g[1]);
    float gg_ = tanhf(g[2]);
    float go_ = sigf(g[3]);
    float c = gf_ * c_prev[idx] + gi_ * gg_;
    c_out[idx] = c;
    h_out[idx] = go_ * tanhf(c);
}

// ---------------- LSTM cell (layer 1) fused with next-step score partials ----------------
// block = (b, h-quarter): after cell update, psc[q][b][s] = sum_{h in quarter} c1[b,h]*KQb[b,s,h]
__global__ __launch_bounds__(256) void cell1s_k(
    const float* __restrict__ partial, const float* __restrict__ biasv,
    const float* __restrict__ c_prev, float* __restrict__ c_out,
    float* __restrict__ h_out, float* __restrict__ y_out, int t,
    const u16* __restrict__ KQb, float* __restrict__ psc)
{
    __shared__ float cs[256];
    int idx = blockIdx.x * 256 + threadIdx.x;     // 32768
    int b = idx >> 10, h = idx & 1023;
    int tid = threadIdx.x, hq = blockIdx.x & 3;
    float g[4];
    #pragma unroll
    for (int gi = 0; gi < 4; gi++){
        int j = (gi << 10) + h;
        float s = biasv[j];
        const float* pp = partial + (size_t)b * kG + j;
        #pragma unroll
        for (int es = 0; es < 16; es++) s += pp[(size_t)es * 32 * kG];
        g[gi] = s;
    }
    float gi_ = sigf(g[0]);
    float gf_ = sigf(g[1]);
    float gg_ = tanhf(g[2]);
    float go_ = sigf(g[3]);
    float c = gf_ * c_prev[idx] + gi_ * gg_;
    float hh = go_ * tanhf(c);
    c_out[idx] = c;
    h_out[idx] = hh;
    y_out[((size_t)b * kT + t) * kH + h] = hh;
    cs[tid] = c;
    __syncthreads();
    // score partial for next step: this thread handles s = tid
    const u16* kp = KQb + (((size_t)((b << 8) | tid)) << 10) + (hq << 8);
    float acc = 0.f;
    #pragma unroll
    for (int i0 = 0; i0 < 32; i0++){
        uint4 kv = *(const uint4*)(kp + i0 * 8);
        const float* cc = &cs[i0 * 8];
        acc += cc[0] * b2f((u16)(kv.x & 0xFFFFu)) + cc[1] * b2f((u16)(kv.x >> 16));
        acc += cc[2] * b2f((u16)(kv.y & 0xFFFFu)) + cc[3] * b2f((u16)(kv.y >> 16));
        acc += cc[4] * b2f((u16)(kv.z & 0xFFFFu)) + cc[5] * b2f((u16)(kv.z >> 16));
        acc += cc[6] * b2f((u16)(kv.w & 0xFFFFu)) + cc[7] * b2f((u16)(kv.w >> 16));
    }
    psc[(((hq << 5) | b) << 8) + tid] = acc;
}

extern "C" void kernel_launch(void* const* d_in, const int* in_sizes, int n_in,
                              void* d_out, int out_size, void* d_ws, size_t ws_size,
                              hipStream_t stream)
{
    const void* inputs = d_in[0];
    const void* enc    = d_in[1];
    const void* enc_c  = d_in[2];
    const void* mask   = d_in[3];
    const void* Wq   = d_in[4];
    const void* bq   = d_in[5];
    const void* Wk   = d_in[6];
    const void* bk   = d_in[7];
    const void* Wv   = d_in[8];
    const void* bv   = d_in[9];
    const void* Wo   = d_in[10];
    const void* bo   = d_in[11];
    const void* Wih0 = d_in[12];
    const void* Whh0 = d_in[13];
    const void* bih0 = d_in[14];
    const void* bhh0 = d_in[15];
    const void* Wih1 = d_in[16];
    const void* Whh1 = d_in[17];
    const void* bih1 = d_in[18];
    const void* bhh1 = d_in[19];
    float* out = (float*)d_out;
    (void)in_sizes; (void)n_in; (void)out_size;

    char* ws = (char*)d_ws;
    size_t off = 0;
    auto alloc = [&](size_t bytes) -> void* {
        void* p = ws + off; off += (bytes + 255) & ~(size_t)255; return p;
    };
    // union: Wkq+Wvo fp32 (precompute, 8MB) alias partial (loop, 10.5MB)
    float* uni    = (float*)alloc((size_t)20 * 32 * kG * 4);
    float* Wkq    = uni;
    float* Wvo    = uni + (size_t)1024 * 1024;
    float* partial= uni;
    u16*  KQb   = (u16*)alloc((size_t)kB * kS * kH * 2);    // [b][s][o]  16.8MB (scale 1/32 folded)
    u16*  Vob   = (u16*)alloc((size_t)kB * kS * kH * 2);    // [b][s][o2] 16.8MB (incl. bvo)
    u16*  WTxb  = (u16*)alloc((size_t)kE * kG * 2);         // Wih0[:,1024:]^T  4.2MB
    u16*  WTcb  = (u16*)alloc((size_t)kH * kG * 2);         // Wih0[:,0:1024]^T 8.4MB
    u16*  WThh0b= (u16*)alloc((size_t)kH * kG * 2);
    u16*  WTih1b= (u16*)alloc((size_t)kH * kG * 2);
    u16*  WThh1b= (u16*)alloc((size_t)kH * kG * 2);
    float* xf    = (float*)alloc((size_t)kB * kT * kE * 4); // 8.4MB [b][t][e]
    float* bkq   = (float*)alloc(1024 * 4);
    float* bvo   = (float*)alloc(1024 * 4);
    float* ubq   = (float*)alloc(1024 * 4);
    float* bof   = (float*)alloc(1024 * 4);
    float* bias01= (float*)alloc(4096 * 4);
    float* bias1 = (float*)alloc(4096 * 4);
    float* cbqbk = (float*)alloc(256);
    float* skbqs = (float*)alloc(kB * kS * 4);
    float* maskflag = (float*)alloc(kB * kS * 4);
    float* psc   = (float*)alloc((size_t)4 * kB * kS * 4);  // [4][b][s] score partials
    float* ctx   = (float*)alloc(kB * kH * 4);
    float* h0f   = (float*)alloc(kB * kH * 4);
    float* c0f   = (float*)alloc(kB * kH * 4);
    float* h1f   = (float*)alloc(kB * kH * 4);
    float* c1f   = (float*)alloc(kB * kH * 4);
    int*   dtflag= (int*)alloc(256);
    // xw (hoisted x@Wih0x^T for all t): 67MB — only if workspace allows
    size_t xw_bytes = (size_t)kB * kT * kG * 4;
    float* xw = nullptr;
    if (off + xw_bytes + 256 <= ws_size) xw = (float*)alloc(xw_bytes);
    const bool use_xw = (xw != nullptr);

    // ---- one-time precompute ----
    detect_dtype_k<<<1, 256, 0, stream>>>(inputs, dtflag);
    prep_mask_k<<<1, 256, 0, stream>>>(mask, maskflag);
    prep_bias_k<<<49, 256, 0, stream>>>(Wq, bq, Wk, bk, bv, Wo, bo,
                                        bih0, bhh0, bih1, bhh1,
                                        bkq, bvo, ubq, bof, bias01, bias1, cbqbk, dtflag);
    copy_inputs_k<<<8192, 256, 0, stream>>>(inputs, xf, dtflag);
    init_state_k<<<128, 256, 0, stream>>>(enc_c, h0f, c0f, h1f, c1f, dtflag);
    transpose_b_k<<<dim3(64, 8),  256, 0, stream>>>(Wih0, 1536, 1024, WTxb,   4096, dtflag);
    transpose_b_k<<<dim3(64, 16), 256, 0, stream>>>(Wih0, 1536, 0,    WTcb,   4096, dtflag);
    transpose_b_k<<<dim3(64, 16), 256, 0, stream>>>(Whh0, 1024, 0,    WThh0b, 4096, dtflag);
    transpose_b_k<<<dim3(64, 16), 256, 0, stream>>>(Wih1, 1024, 0,    WTih1b, 4096, dtflag);
    transpose_b_k<<<dim3(64, 16), 256, 0, stream>>>(Whh1, 1024, 0,    WThh1b, 4096, dtflag);
    gemm_ww_k<0><<<dim3(16, 16), 256, 0, stream>>>(Wk, Wq, Wkq, dtflag);
    gemm_ww_k<1><<<dim3(16, 16), 256, 0, stream>>>(Wv, Wo, Wvo, dtflag);
    gemm_enc_k<<<dim3(128, 16), 256, 0, stream>>>(enc, Wkq, KQb, bkq, 0.03125f, dtflag);
    gemm_enc_k<<<dim3(128, 16), 256, 0, stream>>>(enc, Wvo, Vob, bvo, 1.0f, dtflag);
    skbq_k<<<2048, 256, 0, stream>>>(enc, ubq, cbqbk, skbqs, dtflag);
    if (use_xw)
        xw_k<<<dim3(16, 128), 256, 0, stream>>>(WTxb, xf, xw);
    // initial score partials from c1 init
    scores0_k<<<2048, 256, 0, stream>>>(c1f, KQb, psc);

    // ---- recurrent loop: 5 kernels/step ----
    for (int t = 0; t < kT; t++){
        cv_k<<<256, 256, 0, stream>>>(psc, skbqs, maskflag, Vob, bof, ctx);
        if (use_xw){
            gates1_k<<<dim3(16, 16), 256, 0, stream>>>(WTcb, WThh0b, ctx, h0f, partial);
            cell_k<16, true><<<128, 256, 0, stream>>>(partial, bias01,
                                                      xw + (size_t)t * 32 * kG,
                                                      c0f, c0f, h0f);
        } else {
            gates0_k<<<dim3(16, 20), 256, 0, stream>>>(WTxb, WTcb, WThh0b,
                                                       xf + (size_t)t * kE, ctx, h0f, partial);
            cell_k<20, false><<<128, 256, 0, stream>>>(partial, bias01, nullptr,
                                                       c0f, c0f, h0f);
        }
        gates1_k<<<dim3(16, 16), 256, 0, stream>>>(WTih1b, WThh1b, h0f, h1f, partial);
        cell1s_k<<<128, 256, 0, stream>>>(partial, bias1, c1f, c1f, h1f, out, t, KQb, psc);
    }
}

// Round 3
// 9030.424 us; speedup vs baseline: 1.7451x; 1.3775x over previous
//
#include <hip/hip_runtime.h>

typedef unsigned short u16;
typedef unsigned int   u32;
typedef unsigned char  u8;

constexpr int kB = 32, kT = 128, kS = 256, kE = 512, kH = 1024, kG = 4096;

typedef __attribute__((ext_vector_type(8))) short bfx8;
typedef __attribute__((ext_vector_type(4))) float fx4;

__device__ __forceinline__ float b2f(u16 v){ return __uint_as_float(((u32)v) << 16); }
__device__ __forceinline__ u16  f2b(float f){
    u32 u = __float_as_uint(f);
    return (u16)((u + 0x7FFFu + ((u >> 16) & 1u)) >> 16);
}
__device__ __forceinline__ float sigf(float x){ return 1.f / (1.f + expf(-x)); }
// dt==0: buffer is bf16 (u16); dt==1: buffer is fp32 (validated: fp32 on this harness)
__device__ __forceinline__ float ldin(const void* p, size_t i, int dt){
    return dt ? ((const float*)p)[i] : b2f(((const u16*)p)[i]);
}

// ---------------- input dtype detection (bf16 vs fp32) ----------------
__global__ void detect_dtype_k(const void* __restrict__ inputs, int* __restrict__ dtflag)
{
    __shared__ int bad;
    int t = threadIdx.x;
    if (t == 0) bad = 0;
    __syncthreads();
    const u16* p = (const u16*)inputs;
    int l = 0;
    for (int i = t; i < 4096; i += 256){
        u16 v = p[i];
        int e = (v >> 7) & 0xFF;
        if (v != 0 && (e < 90 || e > 140)) l = 1;
    }
    if (l) atomicOr(&bad, 1);
    __syncthreads();
    if (t == 0) *dtflag = bad;   // 1 = fp32, 0 = bf16
}

// ---------------- mask detection -> maskflag[b][s] = 1.0 (pad) / 0.0 ----------------
__global__ void prep_mask_k(const void* __restrict__ mask, float* __restrict__ maskflag)
{
    __shared__ int bad32, bad16, bad8, evenNZ;
    int t = threadIdx.x;
    if (t == 0){ bad32 = 0; bad16 = 0; bad8 = 0; evenNZ = 0; }
    __syncthreads();
    const u32* w32 = (const u32*)mask;
    const u16* w16 = (const u16*)mask;
    const u8*  w8  = (const u8*)mask;
    int l32 = 0, l16 = 0, l8 = 0, lev = 0;
    for (int i = t; i < 2048; i += 256){ u32 v = w32[i]; l32 |= (v > 1u); }
    for (int i = t; i < 4096; i += 256){
        u16 v = w16[i];
        l16 |= (v != 0 && v != 0x3F80u);
        if ((i & 1) == 0 && v != 0) lev = 1;
    }
    for (int i = t; i < 8192; i += 256){ l8 |= (w8[i] > 1); }
    if (l32) atomicOr(&bad32, 1);
    if (l16) atomicOr(&bad16, 1);
    if (l8)  atomicOr(&bad8, 1);
    if (lev) atomicOr(&evenNZ, 1);
    __syncthreads();
    int mode;                       // 0=int32, 1=bf16, 2=uint8, 3=fp32
    if (!bad32)       mode = 0;
    else if (!bad16)  mode = evenNZ ? 1 : 3;
    else if (!bad8)   mode = 2;
    else              mode = 3;
    for (int i = t; i < kB * kS; i += 256){
        bool m;
        if (mode == 0)      m = (((const int*)mask)[i] != 0);
        else if (mode == 1) m = (w16[i] != 0);
        else if (mode == 2) m = (w8[i] != 0);
        else                m = (((const float*)mask)[i] != 0.f);
        maskflag[i] = m ? 1.f : 0.f;
    }
}

// ---------------- bias / fold-vector precompute ----------------
__global__ void prep_bias_k(const void* __restrict__ Wq, const void* __restrict__ bq,
                            const void* __restrict__ Wk, const void* __restrict__ bk,
                            const void* __restrict__ bv, const void* __restrict__ Wo,
                            const void* __restrict__ bo,
                            const void* __restrict__ bih0, const void* __restrict__ bhh0,
                            const void* __restrict__ bih1, const void* __restrict__ bhh1,
                            float* __restrict__ bkq, float* __restrict__ bvo,
                            float* __restrict__ ubq, float* __restrict__ bof,
                            float* __restrict__ bias01, float* __restrict__ bias1,
                            float* __restrict__ cbqbk, const int* __restrict__ dtflag)
{
    int dt = *dtflag;
    int idx = blockIdx.x * 256 + threadIdx.x;
    if (idx < 1024){
        float s = 0.f;
        for (int i = 0; i < 1024; i++) s += ldin(bk, i, dt) * ldin(Wq, (size_t)i * 1024 + idx, dt);
        bkq[idx] = s;
    } else if (idx < 2048){ int o2 = idx - 1024;
        float s = 0.f;
        for (int h = 0; h < 1024; h++) s += ldin(bv, h, dt) * ldin(Wo, (size_t)o2 * 1024 + h, dt);
        bvo[o2] = s;
    } else if (idx < 3072){ int e = idx - 2048;
        float s = 0.f;
        for (int i = 0; i < 1024; i++) s += ldin(bq, i, dt) * ldin(Wk, (size_t)i * 1024 + e, dt);
        ubq[e] = s;
    } else if (idx < 4096){ int o2 = idx - 3072;
        bof[o2] = ldin(bo, o2, dt);
    } else if (idx < 8192){ int j = idx - 4096;
        bias01[j] = ldin(bih0, j, dt) + ldin(bhh0, j, dt);
    } else if (idx < 12288){ int j = idx - 8192;
        bias1[j] = ldin(bih1, j, dt) + ldin(bhh1, j, dt);
    } else if (idx == 12288){
        float s = 0.f;
        for (int i = 0; i < 1024; i++) s += ldin(bq, i, dt) * ldin(bk, i, dt);
        cbqbk[0] = s;
    }
}

// ---------------- inputs -> fp32 copy, same [B,T,E] layout ----------------
__global__ void copy_inputs_k(const void* __restrict__ inputs, float* __restrict__ xf,
                              const int* __restrict__ dtflag)
{
    int dt = *dtflag;
    int idx = blockIdx.x * 256 + threadIdx.x;   // grid 8192 -> 2097152
    xf[idx] = ldin(inputs, idx, dt);
}

// ---------------- initial states: c0,c1 from enc_c; zero h hi/lo double-buffers ----------------
__global__ void init_state_k(const void* __restrict__ enc_c,
                             float* __restrict__ c0, float* __restrict__ c1,
                             u16* __restrict__ H0h, u16* __restrict__ H0l,
                             u16* __restrict__ H1h, u16* __restrict__ H1l,
                             const int* __restrict__ dtflag)
{
    int dt = *dtflag;
    int idx = blockIdx.x * 256 + threadIdx.x;     // 32768
    int b = idx >> 10, h = idx & 1023;
    float cv = (h < 512) ? ldin(enc_c, (size_t)b * 512 + h, dt)
                         : ldin(enc_c, (size_t)(32 + b) * 512 + (h - 512), dt);
    c0[idx] = cv; c1[idx] = cv;
    H0h[idx] = 0; H0h[32768 + idx] = 0;
    H0l[idx] = 0; H0l[32768 + idx] = 0;
    H1h[idx] = 0; H1h[32768 + idx] = 0;
    H1l[idx] = 0; H1l[32768 + idx] = 0;
}

// ---------------- transpose to bf16: WT[e*ldt + j] = bf16(W[j*ldw + col_off + e]) ----------------
__global__ void transpose_b_k(const void* __restrict__ W, int ldw, int col_off,
                              u16* __restrict__ WT, int ldt, const int* __restrict__ dtflag)
{
    __shared__ float tile[64][65];
    int dt = *dtflag;
    int j0 = blockIdx.x * 64, e0 = blockIdx.y * 64;
    for (int i = 0; i < 16; i++){
        int idx = threadIdx.x + i * 256;
        int jr = idx >> 6, ec = idx & 63;
        tile[jr][ec] = ldin(W, (size_t)(j0 + jr) * ldw + col_off + e0 + ec, dt);
    }
    __syncthreads();
    for (int i = 0; i < 16; i++){
        int idx = threadIdx.x + i * 256;
        int er = idx >> 6, jc = idx & 63;
        WT[(size_t)(e0 + er) * ldt + j0 + jc] = f2b(tile[jc][er]);
    }
}

// ---------------- weight frag reorder: F[((ct*32+ks)*64+l)*8+j] = bf16(W[(ct*16+(l&15))*ldw + col_off + ks*32 + (l>>4)*8 + j]) ----------------
__global__ __launch_bounds__(256) void wfrag_k(const void* __restrict__ W, int ldw, int col_off,
                                               u16* __restrict__ F, const int* __restrict__ dtflag)
{
    int dt = *dtflag;
    int ct = blockIdx.x;                 // 0..255 (16 output cols each)
    #pragma unroll 4
    for (int i = 0; i < 64; i++){
        int flat = threadIdx.x + i * 256;    // 0..16383
        int ks = flat >> 9, r = flat & 511, l = r >> 3, j = r & 7;
        int row = ct * 16 + (l & 15);
        int k = ks * 32 + (l >> 4) * 8 + j;
        F[(size_t)ct * 16384 + flat] = f2b(ldin(W, (size_t)row * ldw + col_off + k, dt));
    }
}

// ---------------- weight-weight fold GEMM: Out[e][c] = sum_k A[k][e] * B(k,c) ----------------
template<int BMODE>
__global__ __launch_bounds__(256) void gemm_ww_k(
    const void* __restrict__ A, const void* __restrict__ Bm,
    float* __restrict__ Out, const int* __restrict__ dtflag)
{
    __shared__ float As[32][68];
    __shared__ float Bs[32][68];
    const int dt = *dtflag;
    const int tid = threadIdx.x;
    const int tile_r = blockIdx.x * 64, tile_c = blockIdx.y * 64;
    const int r0 = (tid & 15) * 4, c0 = (tid >> 4) * 4;
    float acc[16];
    #pragma unroll
    for (int i = 0; i < 16; i++) acc[i] = 0.f;
    for (int k0 = 0; k0 < 1024; k0 += 32){
        int rr = tid & 63, kq = tid >> 6;
        #pragma unroll
        for (int i = 0; i < 8; i++){
            int k = kq * 8 + i;
            As[k][rr] = ldin(A, (size_t)(k0 + k) * 1024 + tile_r + rr, dt);
        }
        #pragma unroll
        for (int i = 0; i < 8; i++){
            int k = kq * 8 + i;
            size_t addr = (BMODE == 0) ? (size_t)(k0 + k) * 1024 + tile_c + rr
                                       : (size_t)(tile_c + rr) * 1024 + k0 + k;
            Bs[k][rr] = ldin(Bm, addr, dt);
        }
        __syncthreads();
        #pragma unroll
        for (int k = 0; k < 32; k++){
            float4 av = *(const float4*)&As[k][r0];
            float4 bv = *(const float4*)&Bs[k][c0];
            acc[0]  += av.x * bv.x; acc[1]  += av.x * bv.y; acc[2]  += av.x * bv.z; acc[3]  += av.x * bv.w;
            acc[4]  += av.y * bv.x; acc[5]  += av.y * bv.y; acc[6]  += av.y * bv.z; acc[7]  += av.y * bv.w;
            acc[8]  += av.z * bv.x; acc[9]  += av.z * bv.y; acc[10] += av.z * bv.z; acc[11] += av.z * bv.w;
            acc[12] += av.w * bv.x; acc[13] += av.w * bv.y; acc[14] += av.w * bv.z; acc[15] += av.w * bv.w;
        }
        __syncthreads();
    }
    #pragma unroll
    for (int i = 0; i < 4; i++){
        int gr = tile_r + r0 + i;
        #pragma unroll
        for (int jj = 0; jj < 4; jj++)
            Out[(size_t)gr * 1024 + tile_c + c0 + jj] = acc[i * 4 + jj];
    }
}

// ---------------- enc-side fold GEMM: bf16 out, row remap (s*32+b) -> [b][s] ----------------
__global__ __launch_bounds__(256) void gemm_enc_k(
    const void* __restrict__ A, const float* __restrict__ Bw,
    u16* __restrict__ Outb, const float* __restrict__ bias, float scale,
    const int* __restrict__ dtflag)
{
    __shared__ float As[32][68];
    __shared__ float Bs[32][68];
    const int dt = *dtflag;
    const int tid = threadIdx.x;
    const int tile_r = blockIdx.x * 64, tile_c = blockIdx.y * 64;
    const int r0 = (tid & 15) * 4, c0 = (tid >> 4) * 4;
    float acc[16];
    #pragma unroll
    for (int i = 0; i < 16; i++) acc[i] = 0.f;
    for (int k0 = 0; k0 < 1024; k0 += 32){
        int rr = tid & 63, kq = tid >> 6;
        size_t base = (size_t)(tile_r + rr) * 1024 + k0 + kq * 8;
        #pragma unroll
        for (int i = 0; i < 8; i++) As[kq * 8 + i][rr] = ldin(A, base + i, dt);
        #pragma unroll
        for (int i = 0; i < 8; i++){
            int k = kq * 8 + i;
            Bs[k][rr] = Bw[(size_t)(k0 + k) * 1024 + tile_c + rr];
        }
        __syncthreads();
        #pragma unroll
        for (int k = 0; k < 32; k++){
            float4 av = *(const float4*)&As[k][r0];
            float4 bv = *(const float4*)&Bs[k][c0];
            acc[0]  += av.x * bv.x; acc[1]  += av.x * bv.y; acc[2]  += av.x * bv.z; acc[3]  += av.x * bv.w;
            acc[4]  += av.y * bv.x; acc[5]  += av.y * bv.y; acc[6]  += av.y * bv.z; acc[7]  += av.y * bv.w;
            acc[8]  += av.z * bv.x; acc[9]  += av.z * bv.y; acc[10] += av.z * bv.z; acc[11] += av.z * bv.w;
            acc[12] += av.w * bv.x; acc[13] += av.w * bv.y; acc[14] += av.w * bv.z; acc[15] += av.w * bv.w;
        }
        __syncthreads();
    }
    #pragma unroll
    for (int i = 0; i < 4; i++){
        int gr = tile_r + r0 + i;
        int b = gr & 31, s = gr >> 5;
        #pragma unroll
        for (int jj = 0; jj < 4; jj++){
            int gc = tile_c + c0 + jj;
            Outb[(((size_t)((b << 8) | s)) << 10) + gc] = f2b((acc[i * 4 + jj] + bias[gc]) * scale);
        }
    }
}

// ---------------- skbqs[b][s] = (bq.K[s,b,:]) * scale ----------------
__global__ __launch_bounds__(256) void skbq_k(
    const void* __restrict__ enc, const float* __restrict__ ubq,
    const float* __restrict__ cbqbk, float* __restrict__ skbqs,
    const int* __restrict__ dtflag)
{
    int dt = *dtflag;
    int w = (blockIdx.x * 256 + threadIdx.x) >> 6;   // 0..8191 = s*32+b
    int lane = threadIdx.x & 63;
    int s = w >> 5, b = w & 31;
    size_t base = (size_t)w * 1024 + lane * 16;
    float acc = 0.f;
    #pragma unroll
    for (int i = 0; i < 16; i++) acc += ubq[lane * 16 + i] * ldin(enc, base + i, dt);
    #pragma unroll
    for (int off = 32; off; off >>= 1) acc += __shfl_down(acc, off, 64);
    if (lane == 0) skbqs[b * 256 + s] = (acc + cbqbk[0]) * 0.03125f;
}

// ---------------- one-time: xw[t][b][j] = x[b,t,:] @ Wih0x^T ----------------
__global__ __launch_bounds__(256) void xw_k(
    const u16* __restrict__ WTx, const float* __restrict__ xf, float* __restrict__ xw)
{
    int jt = blockIdx.x, t = blockIdx.y;
    int j = jt * 256 + threadIdx.x;
    float acc[32];
    #pragma unroll
    for (int b = 0; b < 32; b++) acc[b] = 0.f;
    for (int ec = 0; ec < 8; ec++){
        float w[64];
        const u16* wp = WTx + (size_t)(ec * 64) * kG + j;
        #pragma unroll
        for (int k = 0; k < 64; k++) w[k] = b2f(wp[(size_t)k * kG]);
        #pragma unroll 4
        for (int b = 0; b < 32; b++){
            const float* ab = xf + ((size_t)b * kT + t) * kE + ec * 64;
            float s0 = 0.f, s1 = 0.f;
            #pragma unroll
            for (int k = 0; k < 64; k += 2){ s0 += w[k] * ab[k]; s1 += w[k + 1] * ab[k + 1]; }
            acc[b] += s0 + s1;
        }
    }
    float* po = xw + ((size_t)t * 32) * kG + j;
    #pragma unroll 4
    for (int b = 0; b < 32; b++) po[(size_t)b * kG] = acc[b];
}

// ---------------- prologue: psc[0][b][s] = c1.KQb full dot; psc slices 1..63 = 0 ----------------
__global__ __launch_bounds__(256) void psc0_k(
    const float* __restrict__ c1f, const u16* __restrict__ KQb, float* __restrict__ psc)
{
    int gid = blockIdx.x * 256 + threadIdx.x;         // 0..524287
    if (gid >= 8192) psc[gid] = 0.f;                  // zero slices 1..63
    int w = gid >> 6;                                 // 0..8191
    int lane = threadIdx.x & 63;
    int b = w >> 8, s = w & 255;
    const u16*  kr = KQb + (((size_t)((b << 8) | s)) << 10) + lane * 16;
    const float* cr = c1f + ((size_t)b << 10) + lane * 16;
    float cb[16];
    *(float4*)&cb[0]  = *(const float4*)(cr);
    *(float4*)&cb[4]  = *(const float4*)(cr + 4);
    *(float4*)&cb[8]  = *(const float4*)(cr + 8);
    *(float4*)&cb[12] = *(const float4*)(cr + 12);
    u32 kb[8];
    *(uint4*)&kb[0] = *(const uint4*)(kr);
    *(uint4*)&kb[4] = *(const uint4*)(kr + 8);
    float acc = 0.f;
    #pragma unroll
    for (int i = 0; i < 8; i++){
        acc += cb[2 * i]     * b2f((u16)(kb[i] & 0xFFFFu));
        acc += cb[2 * i + 1] * b2f((u16)(kb[i] >> 16));
    }
    #pragma unroll
    for (int off = 32; off; off >>= 1) acc += __shfl_down(acc, off, 64);
    if (lane == 0) psc[b * 256 + s] = acc;            // slice 0
}

// ---------------- per-step: softmax over 64 psc slices + ctx = attn@Vob + bo -> ctx hi/lo bf16 ----------------
// grid 256 = (b<<3 | ht), ht covers 128 h each
__global__ __launch_bounds__(256) void cv_k(
    const float* __restrict__ psc, const float* __restrict__ skbqs,
    const float* __restrict__ maskflag, const u16* __restrict__ Vob,
    const float* __restrict__ bof, u16* __restrict__ Ch, u16* __restrict__ Cl)
{
    __shared__ float attn[256];
    __shared__ float wred[8];
    __shared__ float2 part[4][64];
    int b = blockIdx.x >> 3, ht = blockIdx.x & 7;
    int tid = threadIdx.x;
    int is = (b << 8) + tid;
    float scv;
    if (maskflag[is] != 0.f) scv = -1e9f;
    else {
        const float* pp = psc + is;
        float s0 = 0.f, s1 = 0.f, s2 = 0.f, s3 = 0.f;
        #pragma unroll
        for (int k = 0; k < 64; k += 4){
            s0 += pp[(size_t)k * 8192];
            s1 += pp[(size_t)(k + 1) * 8192];
            s2 += pp[(size_t)(k + 2) * 8192];
            s3 += pp[(size_t)(k + 3) * 8192];
        }
        scv = (s0 + s1) + (s2 + s3) + skbqs[is];
    }
    float m = scv;
    #pragma unroll
    for (int off = 32; off; off >>= 1) m = fmaxf(m, __shfl_down(m, off, 64));
    if ((tid & 63) == 0) wred[tid >> 6] = m;
    __syncthreads();
    float mm = fmaxf(fmaxf(wred[0], wred[1]), fmaxf(wred[2], wred[3]));
    float ex = expf(scv - mm);
    float ssum = ex;
    #pragma unroll
    for (int off = 32; off; off >>= 1) ssum += __shfl_down(ssum, off, 64);
    if ((tid & 63) == 0) wred[4 + (tid >> 6)] = ssum;
    __syncthreads();
    float tot = (wred[4] + wred[5]) + (wred[6] + wred[7]);
    attn[tid] = ex / tot;
    __syncthreads();
    int hl = tid & 63, scn = tid >> 6;
    int h2 = ht * 128 + hl * 2;
    const u16* vcol = Vob + ((size_t)b << 18) + h2;
    float a0 = 0.f, a1 = 0.f;
    #pragma unroll 8
    for (int s = scn; s < 256; s += 4){
        u32 v = *(const u32*)(vcol + ((size_t)s << 10));
        float at = attn[s];
        a0 += at * b2f((u16)(v & 0xFFFFu));
        a1 += at * b2f((u16)(v >> 16));
    }
    part[scn][hl] = make_float2(a0, a1);
    __syncthreads();
    if (tid < 64){
        float2 p0 = part[0][tid], p1 = part[1][tid], p2 = part[2][tid], p3 = part[3][tid];
        int h = ht * 128 + tid * 2;
        float v0 = p0.x + p1.x + p2.x + p3.x + bof[h];
        float v1 = p0.y + p1.y + p2.y + p3.y + bof[h + 1];
        u16 h0 = f2b(v0), h1 = f2b(v1);
        int base = (b << 10) + h;
        Ch[base] = h0;     Ch[base + 1] = h1;
        Cl[base] = f2b(v0 - b2f(h0));
        Cl[base + 1] = f2b(v1 - b2f(h1));
    }
}

// ---------------- fused MFMA gates + LSTM cell (one layer), 64 blocks x 512 threads ----------------
// Block ht owns output cols {g*1024 + ht*16 + 0..15 : g=0..3} for all 32 b.
// Waves 0-3: K-half A (Fa, actA); waves 4-7: K-half B (Fb, actB). LDS reduce, then cell.
// LAYER==1 additionally: y write, cs -> psc[ht][b][s] score partials for next step.
template<int LAYER>
__global__ __launch_bounds__(512, 1) void gatecell_k(
    const u16* __restrict__ Fa, const u16* __restrict__ Fb,
    const u16* __restrict__ actAh, const u16* __restrict__ actAl,
    const u16* __restrict__ actBh, const u16* __restrict__ actBl,
    const float* __restrict__ biasv, const float* __restrict__ xwrow,
    float* __restrict__ c_state,
    u16* __restrict__ outHh, u16* __restrict__ outHl,
    float* __restrict__ y_out, int t,
    const u16* __restrict__ KQb, float* __restrict__ psc)
{
    __shared__ float red[8][32][64];
    __shared__ float cs[512];
    int ht = blockIdx.x;          // 0..63
    int tid = threadIdx.x, wave = tid >> 6, lane = tid & 63;
    int sel = wave >> 2;
    const u16* F  = sel ? Fb  : Fa;
    const u16* ah = sel ? actBh : actAh;
    const u16* al = sel ? actBl : actAl;
    int ks0 = (wave & 3) * 8;
    int rA = lane & 15, kq = lane >> 4;
    fx4 acc[2][4];
    #pragma unroll
    for (int mt = 0; mt < 2; mt++)
        #pragma unroll
        for (int nt = 0; nt < 4; nt++) acc[mt][nt] = (fx4){0.f, 0.f, 0.f, 0.f};

    #pragma unroll
    for (int ks8 = 0; ks8 < 8; ks8++){
        int ks = ks0 + ks8;
        int koff = ks * 32 + kq * 8;
        bfx8 a_h0 = *(const bfx8*)(ah + (size_t)rA * 1024 + koff);
        bfx8 a_l0 = *(const bfx8*)(al + (size_t)rA * 1024 + koff);
        bfx8 a_h1 = *(const bfx8*)(ah + (size_t)(16 + rA) * 1024 + koff);
        bfx8 a_l1 = *(const bfx8*)(al + (size_t)(16 + rA) * 1024 + koff);
        #pragma unroll
        for (int nt = 0; nt < 4; nt++){
            bfx8 bf = *(const bfx8*)(F + ((size_t)((nt * 64 + ht) * 32 + ks) * 64 + lane) * 8);
            acc[0][nt] = __builtin_amdgcn_mfma_f32_16x16x32_bf16(a_h0, bf, acc[0][nt], 0, 0, 0);
            acc[0][nt] = __builtin_amdgcn_mfma_f32_16x16x32_bf16(a_l0, bf, acc[0][nt], 0, 0, 0);
            acc[1][nt] = __builtin_amdgcn_mfma_f32_16x16x32_bf16(a_h1, bf, acc[1][nt], 0, 0, 0);
            acc[1][nt] = __builtin_amdgcn_mfma_f32_16x16x32_bf16(a_l1, bf, acc[1][nt], 0, 0, 0);
        }
    }
    // C/D layout (m89-verified): col = lane&15, row = (lane>>4)*4 + reg
    #pragma unroll
    for (int mt = 0; mt < 2; mt++)
        #pragma unroll
        for (int nt = 0; nt < 4; nt++)
            #pragma unroll
            for (int i = 0; i < 4; i++)
                red[wave][mt * 16 + kq * 4 + i][nt * 16 + rA] = acc[mt][nt][i];
    __syncthreads();

    // ---- cell phase: thread (b, hl) ----
    int b = tid >> 4, hl = tid & 15;
    int hidx = ht * 16 + hl;
    float g[4];
    #pragma unroll
    for (int gate = 0; gate < 4; gate++){
        float s = biasv[gate * 1024 + hidx];
        if (LAYER == 0) s += xwrow[(b << 12) + gate * 1024 + hidx];
        #pragma unroll
        for (int w = 0; w < 8; w++) s += red[w][b][gate * 16 + hl];
        g[gate] = s;
    }
    float gi_ = sigf(g[0]);
    float gf_ = sigf(g[1]);
    float gg_ = tanhf(g[2]);
    float go_ = sigf(g[3]);
    int cidx = (b << 10) + hidx;
    float c = gf_ * c_state[cidx] + gi_ * gg_;
    c_state[cidx] = c;
    float h = go_ * tanhf(c);
    u16 hh = f2b(h);
    outHh[cidx] = hh;
    outHl[cidx] = f2b(h - b2f(hh));
    if (LAYER == 1){
        y_out[((size_t)b * kT + t) * kH + hidx] = h;
        cs[(b << 4) | hl] = c;
        __syncthreads();
        // ---- psc phase: psc[ht][b2][s] = sum_{hl} c1[b2][ht*16+hl] * KQb[b2][s][ht*16+hl]
        int b2 = tid >> 4, s0 = (tid & 15) << 4;
        float csr[16];
        #pragma unroll
        for (int q = 0; q < 16; q++) csr[q] = cs[(b2 << 4) + q];
        #pragma unroll 4
        for (int s = s0; s < s0 + 16; s++){
            const u16* kp = KQb + (((size_t)((b2 << 8) | s)) << 10) + ht * 16;
            uint4 k0 = *(const uint4*)kp;
            uint4 k1 = *(const uint4*)(kp + 8);
            float a = 0.f;
            a += csr[0]  * b2f((u16)(k0.x & 0xFFFFu)) + csr[1]  * b2f((u16)(k0.x >> 16));
            a += csr[2]  * b2f((u16)(k0.y & 0xFFFFu)) + csr[3]  * b2f((u16)(k0.y >> 16));
            a += csr[4]  * b2f((u16)(k0.z & 0xFFFFu)) + csr[5]  * b2f((u16)(k0.z >> 16));
            a += csr[6]  * b2f((u16)(k0.w & 0xFFFFu)) + csr[7]  * b2f((u16)(k0.w >> 16));
            a += csr[8]  * b2f((u16)(k1.x & 0xFFFFu)) + csr[9]  * b2f((u16)(k1.x >> 16));
            a += csr[10] * b2f((u16)(k1.y & 0xFFFFu)) + csr[11] * b2f((u16)(k1.y >> 16));
            a += csr[12] * b2f((u16)(k1.z & 0xFFFFu)) + csr[13] * b2f((u16)(k1.z >> 16));
            a += csr[14] * b2f((u16)(k1.w & 0xFFFFu)) + csr[15] * b2f((u16)(k1.w >> 16));
            psc[((ht << 5) + b2) * 256 + s] = a;
        }
    }
}

extern "C" void kernel_launch(void* const* d_in, const int* in_sizes, int n_in,
                              void* d_out, int out_size, void* d_ws, size_t ws_size,
                              hipStream_t stream)
{
    const void* inputs = d_in[0];
    const void* enc    = d_in[1];
    const void* enc_c  = d_in[2];
    const void* mask   = d_in[3];
    const void* Wq   = d_in[4];
    const void* bq   = d_in[5];
    const void* Wk   = d_in[6];
    const void* bk   = d_in[7];
    const void* Wv   = d_in[8];
    const void* bv   = d_in[9];
    const void* Wo   = d_in[10];
    const void* bo   = d_in[11];
    const void* Wih0 = d_in[12];
    const void* Whh0 = d_in[13];
    const void* bih0 = d_in[14];
    const void* bhh0 = d_in[15];
    const void* Wih1 = d_in[16];
    const void* Whh1 = d_in[17];
    const void* bih1 = d_in[18];
    const void* bhh1 = d_in[19];
    float* out = (float*)d_out;
    (void)in_sizes; (void)n_in; (void)out_size; (void)ws_size;

    char* ws = (char*)d_ws;
    size_t off = 0;
    auto alloc = [&](size_t bytes) -> void* {
        void* p = ws + off; off += (bytes + 255) & ~(size_t)255; return p;
    };
    // F0c (8.4MB) unions with Wkq+Wvo (2x4.2MB): gemm_ww/gemm_enc consume before wfrag writes
    u16*  F0c  = (u16*)alloc((size_t)kG * kH * 2);
    float* Wkq = (float*)F0c;
    float* Wvo = Wkq + (size_t)1024 * 1024;
    u16*  F0h  = (u16*)alloc((size_t)kG * kH * 2);
    u16*  F1i  = (u16*)alloc((size_t)kG * kH * 2);
    // F1h (8.4MB) unions with xf (8.4MB): xw_k consumes xf before wfrag writes F1h
    u16*  F1h  = (u16*)alloc((size_t)kG * kH * 2);
    float* xf  = (float*)F1h;
    u16*  KQb  = (u16*)alloc((size_t)kB * kS * kH * 2);    // [b][s][o] (scale 1/32 folded)
    u16*  Vob  = (u16*)alloc((size_t)kB * kS * kH * 2);    // [b][s][o2] (incl. bvo)
    u16*  WTxb = (u16*)alloc((size_t)kE * kG * 2);         // Wih0[:,1024:]^T for xw_k
    float* xw  = (float*)alloc((size_t)kB * kT * kG * 4);  // 67MB hoisted x@Wih0x^T
    float* psc = (float*)alloc((size_t)64 * kB * kS * 4);  // [64][b][s] score partials
    u16*  Ch   = (u16*)alloc((size_t)kB * kH * 2);
    u16*  Cl   = (u16*)alloc((size_t)kB * kH * 2);
    u16*  H0h  = (u16*)alloc((size_t)2 * kB * kH * 2);     // double-buffered
    u16*  H0l  = (u16*)alloc((size_t)2 * kB * kH * 2);
    u16*  H1h  = (u16*)alloc((size_t)2 * kB * kH * 2);
    u16*  H1l  = (u16*)alloc((size_t)2 * kB * kH * 2);
    float* c0f = (float*)alloc(kB * kH * 4);
    float* c1f = (float*)alloc(kB * kH * 4);
    float* bkq = (float*)alloc(1024 * 4);
    float* bvo = (float*)alloc(1024 * 4);
    float* ubq = (float*)alloc(1024 * 4);
    float* bof = (float*)alloc(1024 * 4);
    float* bias01 = (float*)alloc(4096 * 4);
    float* bias1  = (float*)alloc(4096 * 4);
    float* cbqbk  = (float*)alloc(256);
    float* skbqs  = (float*)alloc(kB * kS * 4);
    float* maskflag = (float*)alloc(kB * kS * 4);
    int*   dtflag = (int*)alloc(256);

    // ---- one-time precompute ----
    detect_dtype_k<<<1, 256, 0, stream>>>(inputs, dtflag);
    prep_mask_k<<<1, 256, 0, stream>>>(mask, maskflag);
    prep_bias_k<<<49, 256, 0, stream>>>(Wq, bq, Wk, bk, bv, Wo, bo,
                                        bih0, bhh0, bih1, bhh1,
                                        bkq, bvo, ubq, bof, bias01, bias1, cbqbk, dtflag);
    copy_inputs_k<<<8192, 256, 0, stream>>>(inputs, xf, dtflag);
    init_state_k<<<128, 256, 0, stream>>>(enc_c, c0f, c1f, H0h, H0l, H1h, H1l, dtflag);
    transpose_b_k<<<dim3(64, 8), 256, 0, stream>>>(Wih0, 1536, 1024, WTxb, 4096, dtflag);
    gemm_ww_k<0><<<dim3(16, 16), 256, 0, stream>>>(Wk, Wq, Wkq, dtflag);
    gemm_ww_k<1><<<dim3(16, 16), 256, 0, stream>>>(Wv, Wo, Wvo, dtflag);
    gemm_enc_k<<<dim3(128, 16), 256, 0, stream>>>(enc, Wkq, KQb, bkq, 0.03125f, dtflag);
    gemm_enc_k<<<dim3(128, 16), 256, 0, stream>>>(enc, Wvo, Vob, bvo, 1.0f, dtflag);
    skbq_k<<<2048, 256, 0, stream>>>(enc, ubq, cbqbk, skbqs, dtflag);
    xw_k<<<dim3(16, 128), 256, 0, stream>>>(WTxb, xf, xw);           // consumes xf (F1h union)
    wfrag_k<<<256, 256, 0, stream>>>(Wih0, 1536, 0, F0c, dtflag);    // overwrites Wkq/Wvo (done)
    wfrag_k<<<256, 256, 0, stream>>>(Whh0, 1024, 0, F0h, dtflag);
    wfrag_k<<<256, 256, 0, stream>>>(Wih1, 1024, 0, F1i, dtflag);
    wfrag_k<<<256, 256, 0, stream>>>(Whh1, 1024, 0, F1h, dtflag);    // overwrites xf (done)
    psc0_k<<<2048, 256, 0, stream>>>(c1f, KQb, psc);

    // ---- recurrent loop: 3 kernels/step ----
    // h0_t lives in H-slot ((t+1)&1); h0_{t-1} read from slot (t&1). Same for h1.
    for (int t = 0; t < kT; t++){
        int rd = (t & 1) * kB * kH;        // prev-state slot offset (u16 elems)
        int wr = ((t + 1) & 1) * kB * kH;  // new-state slot offset
        cv_k<<<256, 256, 0, stream>>>(psc, skbqs, maskflag, Vob, bof, Ch, Cl);
        gatecell_k<0><<<64, 512, 0, stream>>>(
            F0c, F0h, Ch, Cl, H0h + rd, H0l + rd,
            bias01, xw + (size_t)t * 32 * kG, c0f,
            H0h + wr, H0l + wr, nullptr, t, nullptr, nullptr);
        gatecell_k<1><<<64, 512, 0, stream>>>(
            F1i, F1h, H0h + wr, H0l + wr, H1h + rd, H1l + rd,
            bias1, nullptr, c1f,
            H1h + wr, H1l + wr, out, t, KQb, psc);
    }
}

// Round 4
// 8500.753 us; speedup vs baseline: 1.8538x; 1.0623x over previous
//
#include <hip/hip_runtime.h>

typedef unsigned short u16;
typedef unsigned int   u32;
typedef unsigned char  u8;

constexpr int kB = 32, kT = 128, kS = 256, kE = 512, kH = 1024, kG = 4096;

typedef __attribute__((ext_vector_type(8))) short bfx8;
typedef __attribute__((ext_vector_type(4))) float fx4;

__device__ __forceinline__ float b2f(u16 v){ return __uint_as_float(((u32)v) << 16); }
__device__ __forceinline__ u16  f2b(float f){
    u32 u = __float_as_uint(f);
    return (u16)((u + 0x7FFFu + ((u >> 16) & 1u)) >> 16);
}
__device__ __forceinline__ float sigf(float x){ return 1.f / (1.f + expf(-x)); }
// dt==0: buffer is bf16 (u16); dt==1: buffer is fp32 (validated: fp32 on this harness)
__device__ __forceinline__ float ldin(const void* p, size_t i, int dt){
    return dt ? ((const float*)p)[i] : b2f(((const u16*)p)[i]);
}

// ---------------- input dtype detection (bf16 vs fp32) ----------------
__global__ void detect_dtype_k(const void* __restrict__ inputs, int* __restrict__ dtflag)
{
    __shared__ int bad;
    int t = threadIdx.x;
    if (t == 0) bad = 0;
    __syncthreads();
    const u16* p = (const u16*)inputs;
    int l = 0;
    for (int i = t; i < 4096; i += 256){
        u16 v = p[i];
        int e = (v >> 7) & 0xFF;
        if (v != 0 && (e < 90 || e > 140)) l = 1;
    }
    if (l) atomicOr(&bad, 1);
    __syncthreads();
    if (t == 0) *dtflag = bad;   // 1 = fp32, 0 = bf16
}

// ---------------- mask detection -> maskflag[b][s] = 1.0 (pad) / 0.0 ----------------
__global__ void prep_mask_k(const void* __restrict__ mask, float* __restrict__ maskflag)
{
    __shared__ int bad32, bad16, bad8, evenNZ;
    int t = threadIdx.x;
    if (t == 0){ bad32 = 0; bad16 = 0; bad8 = 0; evenNZ = 0; }
    __syncthreads();
    const u32* w32 = (const u32*)mask;
    const u16* w16 = (const u16*)mask;
    const u8*  w8  = (const u8*)mask;
    int l32 = 0, l16 = 0, l8 = 0, lev = 0;
    for (int i = t; i < 2048; i += 256){ u32 v = w32[i]; l32 |= (v > 1u); }
    for (int i = t; i < 4096; i += 256){
        u16 v = w16[i];
        l16 |= (v != 0 && v != 0x3F80u);
        if ((i & 1) == 0 && v != 0) lev = 1;
    }
    for (int i = t; i < 8192; i += 256){ l8 |= (w8[i] > 1); }
    if (l32) atomicOr(&bad32, 1);
    if (l16) atomicOr(&bad16, 1);
    if (l8)  atomicOr(&bad8, 1);
    if (lev) atomicOr(&evenNZ, 1);
    __syncthreads();
    int mode;                       // 0=int32, 1=bf16, 2=uint8, 3=fp32
    if (!bad32)       mode = 0;
    else if (!bad16)  mode = evenNZ ? 1 : 3;
    else if (!bad8)   mode = 2;
    else              mode = 3;
    for (int i = t; i < kB * kS; i += 256){
        bool m;
        if (mode == 0)      m = (((const int*)mask)[i] != 0);
        else if (mode == 1) m = (w16[i] != 0);
        else if (mode == 2) m = (w8[i] != 0);
        else                m = (((const float*)mask)[i] != 0.f);
        maskflag[i] = m ? 1.f : 0.f;
    }
}

// ---------------- bias / fold-vector precompute ----------------
__global__ void prep_bias_k(const void* __restrict__ Wq, const void* __restrict__ bq,
                            const void* __restrict__ Wk, const void* __restrict__ bk,
                            const void* __restrict__ bv, const void* __restrict__ Wo,
                            const void* __restrict__ bo,
                            const void* __restrict__ bih0, const void* __restrict__ bhh0,
                            const void* __restrict__ bih1, const void* __restrict__ bhh1,
                            float* __restrict__ bkq, float* __restrict__ bvo,
                            float* __restrict__ ubq, float* __restrict__ bof,
                            float* __restrict__ bias01, float* __restrict__ bias1,
                            float* __restrict__ cbqbk, const int* __restrict__ dtflag)
{
    int dt = *dtflag;
    int idx = blockIdx.x * 256 + threadIdx.x;
    if (idx < 1024){
        float s = 0.f;
        for (int i = 0; i < 1024; i++) s += ldin(bk, i, dt) * ldin(Wq, (size_t)i * 1024 + idx, dt);
        bkq[idx] = s;
    } else if (idx < 2048){ int o2 = idx - 1024;
        float s = 0.f;
        for (int h = 0; h < 1024; h++) s += ldin(bv, h, dt) * ldin(Wo, (size_t)o2 * 1024 + h, dt);
        bvo[o2] = s;
    } else if (idx < 3072){ int e = idx - 2048;
        float s = 0.f;
        for (int i = 0; i < 1024; i++) s += ldin(bq, i, dt) * ldin(Wk, (size_t)i * 1024 + e, dt);
        ubq[e] = s;
    } else if (idx < 4096){ int o2 = idx - 3072;
        bof[o2] = ldin(bo, o2, dt);
    } else if (idx < 8192){ int j = idx - 4096;
        bias01[j] = ldin(bih0, j, dt) + ldin(bhh0, j, dt);
    } else if (idx < 12288){ int j = idx - 8192;
        bias1[j] = ldin(bih1, j, dt) + ldin(bhh1, j, dt);
    } else if (idx == 12288){
        float s = 0.f;
        for (int i = 0; i < 1024; i++) s += ldin(bq, i, dt) * ldin(bk, i, dt);
        cbqbk[0] = s;
    }
}

// ---------------- initial states: c0,c1 from enc_c; zero h hi/lo double-buffers ----------------
__global__ void init_state_k(const void* __restrict__ enc_c,
                             float* __restrict__ c0, float* __restrict__ c1,
                             u16* __restrict__ H0h, u16* __restrict__ H0l,
                             u16* __restrict__ H1h, u16* __restrict__ H1l,
                             const int* __restrict__ dtflag)
{
    int dt = *dtflag;
    int idx = blockIdx.x * 256 + threadIdx.x;     // 32768
    int b = idx >> 10, h = idx & 1023;
    float cv = (h < 512) ? ldin(enc_c, (size_t)b * 512 + h, dt)
                         : ldin(enc_c, (size_t)(32 + b) * 512 + (h - 512), dt);
    c0[idx] = cv; c1[idx] = cv;
    H0h[idx] = 0; H0h[32768 + idx] = 0;
    H0l[idx] = 0; H0l[32768 + idx] = 0;
    H1h[idx] = 0; H1h[32768 + idx] = 0;
    H1l[idx] = 0; H1l[32768 + idx] = 0;
}

// ---------------- elementwise hi/lo bf16 split (same layout) ----------------
__global__ void split_plain_k(const void* __restrict__ src, u16* __restrict__ Oh,
                              u16* __restrict__ Ol, int n, const int* __restrict__ dtflag)
{
    int dt = *dtflag;
    int idx = blockIdx.x * 256 + threadIdx.x;
    if (idx >= n) return;
    float v = ldin(src, idx, dt);
    u16 h = f2b(v);
    Oh[idx] = h;
    Ol[idx] = f2b(v - b2f(h));
}

// ---------------- x split with (b,t)->m remap: X[(t*32+b)*512 + e] ----------------
__global__ void split_x_k(const void* __restrict__ inputs, u16* __restrict__ Xh,
                          u16* __restrict__ Xl, const int* __restrict__ dtflag)
{
    int dt = *dtflag;
    int idx = blockIdx.x * 256 + threadIdx.x;        // 2097152 = 32*128*512
    int b = idx >> 16, t = (idx >> 9) & 127, e = idx & 511;
    float v = ldin(inputs, idx, dt);
    u16 h = f2b(v);
    size_t o = ((size_t)(t * 32 + b) << 9) + e;
    Xh[o] = h;
    Xl[o] = f2b(v - b2f(h));
}

// ---------------- transpose + hi/lo split: O[c][r] = split(in[r][col_off + c]) ----------------
__global__ void tsplit_k(const void* __restrict__ W, int ldw, int col_off,
                         u16* __restrict__ Oh, u16* __restrict__ Ol, int ldo,
                         const int* __restrict__ dtflag)
{
    __shared__ float tile[64][65];
    int dt = *dtflag;
    int r0 = blockIdx.x * 64, c0 = blockIdx.y * 64;
    for (int i = 0; i < 16; i++){
        int idx = threadIdx.x + i * 256;
        int rr = idx >> 6, cc = idx & 63;
        tile[rr][cc] = ldin(W, (size_t)(r0 + rr) * ldw + col_off + c0 + cc, dt);
    }
    __syncthreads();
    for (int i = 0; i < 16; i++){
        int idx = threadIdx.x + i * 256;
        int cr = idx >> 6, rc = idx & 63;
        float v = tile[rc][cr];
        u16 h = f2b(v);
        size_t o = (size_t)(c0 + cr) * ldo + r0 + rc;
        Oh[o] = h;
        Ol[o] = f2b(v - b2f(h));
    }
}

// ---------------- weight frag reorder: F[ct][ks][lane][j], KSS k-slices ----------------
__global__ __launch_bounds__(256) void wfrag_k(const void* __restrict__ W, int ldw, int col_off,
                                               u16* __restrict__ F, int KSS,
                                               const int* __restrict__ dtflag)
{
    int dt = *dtflag;
    int ct = blockIdx.x;                 // 0..255 (16 output cols each)
    int iters = KSS * 2;                 // KSS*512 / 256
    for (int i = 0; i < iters; i++){
        int flat = threadIdx.x + i * 256;
        int ks = flat >> 9, r = flat & 511, l = r >> 3, j = r & 7;
        int row = ct * 16 + (l & 15);
        int k = ks * 32 + (l >> 4) * 8 + j;
        F[(size_t)ct * (KSS * 512) + flat] = f2b(ldin(W, (size_t)row * ldw + col_off + k, dt));
    }
}

// ---------------- generic hi/lo MFMA GEMM: Out[m][n] = sum_k A[m][k]*B[k][n], K=1024 ----------------
// A: m-major hi/lo bf16 (ldA). B: k-major hi/lo bf16 (ldB). 64x64 tile/block, 4 waves.
// EPI 0: OutH/OutL hi/lo fp32-split bf16 at [m*ldO+n].  EPI 1: bf16 out, remap m=s*32+b -> [b][s], +bias, *scale.
template<int EPI>
__global__ __launch_bounds__(256) void gemm_hilo_k(
    const u16* __restrict__ Ah, const u16* __restrict__ Al, int ldA,
    const u16* __restrict__ Bh, const u16* __restrict__ Bl, int ldB,
    u16* __restrict__ OutH, u16* __restrict__ OutL, int ldO,
    const float* __restrict__ bias, float scale)
{
    __shared__ __align__(16) u16 Bsh[64][40];
    __shared__ __align__(16) u16 Bsl[64][40];
    int tid = threadIdx.x, wave = tid >> 6, lane = tid & 63;
    int m0 = blockIdx.x * 64, n0 = blockIdx.y * 64;
    int rA = lane & 15, kq = lane >> 4;
    fx4 acc[4];
    #pragma unroll
    for (int nt = 0; nt < 4; nt++) acc[nt] = (fx4){0.f, 0.f, 0.f, 0.f};
    int skk = tid >> 3, snn = (tid & 7) * 8;
    for (int k0 = 0; k0 < 1024; k0 += 32){
        bfx8 vh = *(const bfx8*)(Bh + (size_t)(k0 + skk) * ldB + n0 + snn);
        bfx8 vl = *(const bfx8*)(Bl + (size_t)(k0 + skk) * ldB + n0 + snn);
        __syncthreads();
        #pragma unroll
        for (int q = 0; q < 8; q++){ Bsh[snn + q][skk] = (u16)vh[q]; Bsl[snn + q][skk] = (u16)vl[q]; }
        __syncthreads();
        size_t abase = (size_t)(m0 + wave * 16 + rA) * ldA + k0 + kq * 8;
        bfx8 a_h = *(const bfx8*)(Ah + abase);
        bfx8 a_l = *(const bfx8*)(Al + abase);
        #pragma unroll
        for (int nt = 0; nt < 4; nt++){
            bfx8 b_h = *(const bfx8*)&Bsh[nt * 16 + rA][kq * 8];
            bfx8 b_l = *(const bfx8*)&Bsl[nt * 16 + rA][kq * 8];
            acc[nt] = __builtin_amdgcn_mfma_f32_16x16x32_bf16(a_h, b_h, acc[nt], 0, 0, 0);
            acc[nt] = __builtin_amdgcn_mfma_f32_16x16x32_bf16(a_h, b_l, acc[nt], 0, 0, 0);
            acc[nt] = __builtin_amdgcn_mfma_f32_16x16x32_bf16(a_l, b_h, acc[nt], 0, 0, 0);
        }
    }
    #pragma unroll
    for (int nt = 0; nt < 4; nt++){
        #pragma unroll
        for (int i = 0; i < 4; i++){
            int m = m0 + wave * 16 + kq * 4 + i;
            int n = n0 + nt * 16 + rA;
            float v = acc[nt][i];
            if (EPI == 0){
                u16 h = f2b(v);
                OutH[(size_t)m * ldO + n] = h;
                OutL[(size_t)m * ldO + n] = f2b(v - b2f(h));
            } else {
                float v2 = (v + bias[n]) * scale;
                OutH[(((size_t)(((m & 31) << 8) | (m >> 5))) << 10) + n] = f2b(v2);
            }
        }
    }
}

// ---------------- skbqs[b][s] = (bq.K[s,b,:]) * scale ----------------
__global__ __launch_bounds__(256) void skbq_k(
    const void* __restrict__ enc, const float* __restrict__ ubq,
    const float* __restrict__ cbqbk, float* __restrict__ skbqs,
    const int* __restrict__ dtflag)
{
    int dt = *dtflag;
    int w = (blockIdx.x * 256 + threadIdx.x) >> 6;   // 0..8191 = s*32+b
    int lane = threadIdx.x & 63;
    int s = w >> 5, b = w & 31;
    size_t base = (size_t)w * 1024 + lane * 16;
    float acc = 0.f;
    #pragma unroll
    for (int i = 0; i < 16; i++) acc += ubq[lane * 16 + i] * ldin(enc, base + i, dt);
    #pragma unroll
    for (int off = 32; off; off >>= 1) acc += __shfl_down(acc, off, 64);
    if (lane == 0) skbqs[b * 256 + s] = (acc + cbqbk[0]) * 0.03125f;
}

// ---------------- prologue: psc[0][b][s] = c1.KQb full dot; psc slices 1..63 = 0 ----------------
__global__ __launch_bounds__(256) void psc0_k(
    const float* __restrict__ c1f, const u16* __restrict__ KQb, float* __restrict__ psc)
{
    int gid = blockIdx.x * 256 + threadIdx.x;         // 0..524287
    if (gid >= 8192) psc[gid] = 0.f;                  // zero slices 1..63
    int w = gid >> 6;                                 // 0..8191
    int lane = threadIdx.x & 63;
    int b = w >> 8, s = w & 255;
    const u16*  kr = KQb + (((size_t)((b << 8) | s)) << 10) + lane * 16;
    const float* cr = c1f + ((size_t)b << 10) + lane * 16;
    float cb[16];
    *(float4*)&cb[0]  = *(const float4*)(cr);
    *(float4*)&cb[4]  = *(const float4*)(cr + 4);
    *(float4*)&cb[8]  = *(const float4*)(cr + 8);
    *(float4*)&cb[12] = *(const float4*)(cr + 12);
    u32 kb[8];
    *(uint4*)&kb[0] = *(const uint4*)(kr);
    *(uint4*)&kb[4] = *(const uint4*)(kr + 8);
    float acc = 0.f;
    #pragma unroll
    for (int i = 0; i < 8; i++){
        acc += cb[2 * i]     * b2f((u16)(kb[i] & 0xFFFFu));
        acc += cb[2 * i + 1] * b2f((u16)(kb[i] >> 16));
    }
    #pragma unroll
    for (int off = 32; off; off >>= 1) acc += __shfl_down(acc, off, 64);
    if (lane == 0) psc[b * 256 + s] = acc;            // slice 0
}

// ---------------- per-step: softmax over 64 psc slices + ctx = attn@Vob + bo -> ctx hi/lo bf16 ----------------
__global__ __launch_bounds__(256) void cv_k(
    const float* __restrict__ psc, const float* __restrict__ skbqs,
    const float* __restrict__ maskflag, const u16* __restrict__ Vob,
    const float* __restrict__ bof, u16* __restrict__ Ch, u16* __restrict__ Cl)
{
    __shared__ float attn[256];
    __shared__ float wred[8];
    __shared__ float2 part[4][64];
    int b = blockIdx.x >> 3, ht = blockIdx.x & 7;
    int tid = threadIdx.x;
    int is = (b << 8) + tid;
    float scv;
    if (maskflag[is] != 0.f) scv = -1e9f;
    else {
        const float* pp = psc + is;
        float s0 = 0.f, s1 = 0.f, s2 = 0.f, s3 = 0.f;
        #pragma unroll
        for (int k = 0; k < 64; k += 4){
            s0 += pp[(size_t)k * 8192];
            s1 += pp[(size_t)(k + 1) * 8192];
            s2 += pp[(size_t)(k + 2) * 8192];
            s3 += pp[(size_t)(k + 3) * 8192];
        }
        scv = (s0 + s1) + (s2 + s3) + skbqs[is];
    }
    float m = scv;
    #pragma unroll
    for (int off = 32; off; off >>= 1) m = fmaxf(m, __shfl_down(m, off, 64));
    if ((tid & 63) == 0) wred[tid >> 6] = m;
    __syncthreads();
    float mm = fmaxf(fmaxf(wred[0], wred[1]), fmaxf(wred[2], wred[3]));
    float ex = expf(scv - mm);
    float ssum = ex;
    #pragma unroll
    for (int off = 32; off; off >>= 1) ssum += __shfl_down(ssum, off, 64);
    if ((tid & 63) == 0) wred[4 + (tid >> 6)] = ssum;
    __syncthreads();
    float tot = (wred[4] + wred[5]) + (wred[6] + wred[7]);
    attn[tid] = ex / tot;
    __syncthreads();
    int hl = tid & 63, scn = tid >> 6;
    int h2 = ht * 128 + hl * 2;
    const u16* vcol = Vob + ((size_t)b << 18) + h2;
    float a0 = 0.f, a1 = 0.f;
    #pragma unroll 8
    for (int s = scn; s < 256; s += 4){
        u32 v = *(const u32*)(vcol + ((size_t)s << 10));
        float at = attn[s];
        a0 += at * b2f((u16)(v & 0xFFFFu));
        a1 += at * b2f((u16)(v >> 16));
    }
    part[scn][hl] = make_float2(a0, a1);
    __syncthreads();
    if (tid < 64){
        float2 p0 = part[0][tid], p1 = part[1][tid], p2 = part[2][tid], p3 = part[3][tid];
        int h = ht * 128 + tid * 2;
        float v0 = p0.x + p1.x + p2.x + p3.x + bof[h];
        float v1 = p0.y + p1.y + p2.y + p3.y + bof[h + 1];
        u16 h0 = f2b(v0), h1 = f2b(v1);
        int base = (b << 10) + h;
        Ch[base] = h0;     Ch[base + 1] = h1;
        Cl[base] = f2b(v0 - b2f(h0));
        Cl[base + 1] = f2b(v1 - b2f(h1));
    }
}

// ---------------- fused MFMA gates + LSTM cell, 64 blocks x 512 threads ----------------
// LAYER 0: K-ranges ctx(32 ks), h0(32 ks), x(16 ks, ld 512) = 80 slices over 8 waves (10 each).
// LAYER 1: h0(32), h1(32) = 64 slices over 8 waves (8 each); fused psc for next step.
template<int LAYER>
__global__ __launch_bounds__(512, 1) void gatecell_k(
    const u16* __restrict__ f0, const u16* __restrict__ f1, const u16* __restrict__ f2,
    const u16* __restrict__ a0h, const u16* __restrict__ a0l,
    const u16* __restrict__ a1h, const u16* __restrict__ a1l,
    const u16* __restrict__ a2h, const u16* __restrict__ a2l,
    const float* __restrict__ biasv, float* __restrict__ c_state,
    u16* __restrict__ outHh, u16* __restrict__ outHl,
    float* __restrict__ y_out, int t,
    const u16* __restrict__ KQb, float* __restrict__ psc)
{
    __shared__ float red[8][32][64];
    __shared__ float cs[512];
    int ht = blockIdx.x;          // 0..63
    int tid = threadIdx.x, wave = tid >> 6, lane = tid & 63;
    int rA = lane & 15, kq = lane >> 4;
    constexpr int NSL = (LAYER == 0) ? 10 : 8;
    fx4 acc[2][4];
    #pragma unroll
    for (int mt = 0; mt < 2; mt++)
        #pragma unroll
        for (int nt = 0; nt < 4; nt++) acc[mt][nt] = (fx4){0.f, 0.f, 0.f, 0.f};

    #pragma unroll
    for (int si = 0; si < NSL; si++){
        int s = wave * NSL + si;
        const u16 *F, *ah, *al; int ks, ld, KSSF;
        if (LAYER == 0){
            if (s < 32)      { F = f0; ks = s;      ah = a0h; al = a0l; ld = 1024; KSSF = 32; }
            else if (s < 64) { F = f1; ks = s - 32; ah = a1h; al = a1l; ld = 1024; KSSF = 32; }
            else             { F = f2; ks = s - 64; ah = a2h; al = a2l; ld = 512;  KSSF = 16; }
        } else {
            if (s < 32)      { F = f0; ks = s;      ah = a0h; al = a0l; }
            else             { F = f1; ks = s - 32; ah = a1h; al = a1l; }
            ld = 1024; KSSF = 32;
        }
        int koff = ks * 32 + kq * 8;
        bfx8 a_h0 = *(const bfx8*)(ah + (size_t)rA * ld + koff);
        bfx8 a_l0 = *(const bfx8*)(al + (size_t)rA * ld + koff);
        bfx8 a_h1 = *(const bfx8*)(ah + (size_t)(16 + rA) * ld + koff);
        bfx8 a_l1 = *(const bfx8*)(al + (size_t)(16 + rA) * ld + koff);
        #pragma unroll
        for (int nt = 0; nt < 4; nt++){
            bfx8 bf = *(const bfx8*)(F + ((size_t)((nt * 64 + ht) * KSSF + ks) * 64 + lane) * 8);
            acc[0][nt] = __builtin_amdgcn_mfma_f32_16x16x32_bf16(a_h0, bf, acc[0][nt], 0, 0, 0);
            acc[0][nt] = __builtin_amdgcn_mfma_f32_16x16x32_bf16(a_l0, bf, acc[0][nt], 0, 0, 0);
            acc[1][nt] = __builtin_amdgcn_mfma_f32_16x16x32_bf16(a_h1, bf, acc[1][nt], 0, 0, 0);
            acc[1][nt] = __builtin_amdgcn_mfma_f32_16x16x32_bf16(a_l1, bf, acc[1][nt], 0, 0, 0);
        }
    }
    // C/D layout (m89-verified): col = lane&15, row = (lane>>4)*4 + reg
    #pragma unroll
    for (int mt = 0; mt < 2; mt++)
        #pragma unroll
        for (int nt = 0; nt < 4; nt++)
            #pragma unroll
            for (int i = 0; i < 4; i++)
                red[wave][mt * 16 + kq * 4 + i][nt * 16 + rA] = acc[mt][nt][i];
    __syncthreads();

    // ---- cell phase: thread (b, hl) ----
    int b = tid >> 4, hl = tid & 15;
    int hidx = ht * 16 + hl;
    float g[4];
    #pragma unroll
    for (int gate = 0; gate < 4; gate++){
        float s = biasv[gate * 1024 + hidx];
        #pragma unroll
        for (int w = 0; w < 8; w++) s += red[w][b][gate * 16 + hl];
        g[gate] = s;
    }
    float gi_ = sigf(g[0]);
    float gf_ = sigf(g[1]);
    float gg_ = tanhf(g[2]);
    float go_ = sigf(g[3]);
    int cidx = (b << 10) + hidx;
    float c = gf_ * c_state[cidx] + gi_ * gg_;
    c_state[cidx] = c;
    float h = go_ * tanhf(c);
    u16 hh = f2b(h);
    outHh[cidx] = hh;
    outHl[cidx] = f2b(h - b2f(hh));
    if (LAYER == 1){
        y_out[((size_t)b * kT + t) * kH + hidx] = h;
        cs[(b << 4) | hl] = c;
        __syncthreads();
        // ---- psc phase: psc[ht][b2][s] = sum_{hl} c1[b2][ht*16+hl] * KQb[b2][s][ht*16+hl]
        int b2 = tid >> 4, s0 = (tid & 15) << 4;
        float csr[16];
        #pragma unroll
        for (int q = 0; q < 16; q++) csr[q] = cs[(b2 << 4) + q];
        #pragma unroll 4
        for (int s = s0; s < s0 + 16; s++){
            const u16* kp = KQb + (((size_t)((b2 << 8) | s)) << 10) + ht * 16;
            uint4 k0 = *(const uint4*)kp;
            uint4 k1 = *(const uint4*)(kp + 8);
            float a = 0.f;
            a += csr[0]  * b2f((u16)(k0.x & 0xFFFFu)) + csr[1]  * b2f((u16)(k0.x >> 16));
            a += csr[2]  * b2f((u16)(k0.y & 0xFFFFu)) + csr[3]  * b2f((u16)(k0.y >> 16));
            a += csr[4]  * b2f((u16)(k0.z & 0xFFFFu)) + csr[5]  * b2f((u16)(k0.z >> 16));
            a += csr[6]  * b2f((u16)(k0.w & 0xFFFFu)) + csr[7]  * b2f((u16)(k0.w >> 16));
            a += csr[8]  * b2f((u16)(k1.x & 0xFFFFu)) + csr[9]  * b2f((u16)(k1.x >> 16));
            a += csr[10] * b2f((u16)(k1.y & 0xFFFFu)) + csr[11] * b2f((u16)(k1.y >> 16));
            a += csr[12] * b2f((u16)(k1.z & 0xFFFFu)) + csr[13] * b2f((u16)(k1.z >> 16));
            a += csr[14] * b2f((u16)(k1.w & 0xFFFFu)) + csr[15] * b2f((u16)(k1.w >> 16));
            psc[((ht << 5) + b2) * 256 + s] = a;
        }
    }
}

extern "C" void kernel_launch(void* const* d_in, const int* in_sizes, int n_in,
                              void* d_out, int out_size, void* d_ws, size_t ws_size,
                              hipStream_t stream)
{
    const void* inputs = d_in[0];
    const void* enc    = d_in[1];
    const void* enc_c  = d_in[2];
    const void* mask   = d_in[3];
    const void* Wq   = d_in[4];
    const void* bq   = d_in[5];
    const void* Wk   = d_in[6];
    const void* bk   = d_in[7];
    const void* Wv   = d_in[8];
    const void* bv   = d_in[9];
    const void* Wo   = d_in[10];
    const void* bo   = d_in[11];
    const void* Wih0 = d_in[12];
    const void* Whh0 = d_in[13];
    const void* bih0 = d_in[14];
    const void* bhh0 = d_in[15];
    const void* Wih1 = d_in[16];
    const void* Whh1 = d_in[17];
    const void* bih1 = d_in[18];
    const void* bhh1 = d_in[19];
    float* out = (float*)d_out;
    (void)in_sizes; (void)n_in; (void)out_size; (void)ws_size;

    char* ws = (char*)d_ws;
    size_t off = 0;
    auto alloc = [&](size_t bytes) -> void* {
        void* p = ws + off; off += (bytes + 255) & ~(size_t)255; return p;
    };
    // POOL_A (37.75MB): Eh/El (split enc, dead after enc GEMMs)  ||  F0c,F0h,F1i,F1h,F0x (wfrag, loop)
    char* poolA = (char*)alloc((size_t)37748736);
    u16* Eh  = (u16*)poolA;                              // 16.8MB
    u16* El  = (u16*)(poolA + 16777216);
    u16* F0c = (u16*)poolA;                              // 8.4MB each
    u16* F0h = (u16*)(poolA + 8388608);
    u16* F1i = (u16*)(poolA + 16777216);
    u16* F1h = (u16*)(poolA + 25165824);
    u16* F0x = (u16*)(poolA + 33554432);                 // 4.2MB
    // POOL_B (16.8MB): ww-GEMM operand splits (dead after ww GEMMs)
    char* poolB = (char*)alloc((size_t)16777216);
    u16* Akh  = (u16*)poolB;
    u16* Akl  = (u16*)(poolB + 2097152);
    u16* Bqh  = (u16*)(poolB + 4194304);
    u16* Bql  = (u16*)(poolB + 6291456);
    u16* Avh  = (u16*)(poolB + 8388608);
    u16* Avl  = (u16*)(poolB + 10485760);
    u16* Both = (u16*)(poolB + 12582912);
    u16* Botl = (u16*)(poolB + 14680064);
    u16*  KQb  = (u16*)alloc((size_t)kB * kS * kH * 2);    // [b][s][o] (scale 1/32 folded)
    u16*  Vob  = (u16*)alloc((size_t)kB * kS * kH * 2);    // [b][s][o2] (incl. bvo)
    u16*  Xh   = (u16*)alloc((size_t)kB * kT * kE * 2);    // [t*32+b][e]
    u16*  Xl   = (u16*)alloc((size_t)kB * kT * kE * 2);
    u16*  Wkqh = (u16*)alloc((size_t)kH * kH * 2);
    u16*  Wkql = (u16*)alloc((size_t)kH * kH * 2);
    u16*  Wvoh = (u16*)alloc((size_t)kH * kH * 2);
    u16*  Wvol = (u16*)alloc((size_t)kH * kH * 2);
    float* psc = (float*)alloc((size_t)64 * kB * kS * 4);  // [64][b][s] score partials
    u16*  Ch   = (u16*)alloc((size_t)kB * kH * 2);
    u16*  Cl   = (u16*)alloc((size_t)kB * kH * 2);
    u16*  H0h  = (u16*)alloc((size_t)2 * kB * kH * 2);     // double-buffered
    u16*  H0l  = (u16*)alloc((size_t)2 * kB * kH * 2);
    u16*  H1h  = (u16*)alloc((size_t)2 * kB * kH * 2);
    u16*  H1l  = (u16*)alloc((size_t)2 * kB * kH * 2);
    float* c0f = (float*)alloc(kB * kH * 4);
    float* c1f = (float*)alloc(kB * kH * 4);
    float* bkq = (float*)alloc(1024 * 4);
    float* bvo = (float*)alloc(1024 * 4);
    float* ubq = (float*)alloc(1024 * 4);
    float* bof = (float*)alloc(1024 * 4);
    float* bias01 = (float*)alloc(4096 * 4);
    float* bias1  = (float*)alloc(4096 * 4);
    float* cbqbk  = (float*)alloc(256);
    float* skbqs  = (float*)alloc(kB * kS * 4);
    float* maskflag = (float*)alloc(kB * kS * 4);
    int*   dtflag = (int*)alloc(256);

    // ---- one-time precompute ----
    detect_dtype_k<<<1, 256, 0, stream>>>(inputs, dtflag);
    prep_mask_k<<<1, 256, 0, stream>>>(mask, maskflag);
    prep_bias_k<<<49, 256, 0, stream>>>(Wq, bq, Wk, bk, bv, Wo, bo,
                                        bih0, bhh0, bih1, bhh1,
                                        bkq, bvo, ubq, bof, bias01, bias1, cbqbk, dtflag);
    init_state_k<<<128, 256, 0, stream>>>(enc_c, c0f, c1f, H0h, H0l, H1h, H1l, dtflag);
    // splits for attention-fold GEMMs
    split_plain_k<<<32768, 256, 0, stream>>>(enc, Eh, El, 8388608, dtflag);
    split_plain_k<<<4096, 256, 0, stream>>>(Wq, Bqh, Bql, 1048576, dtflag);
    tsplit_k<<<dim3(16, 16), 256, 0, stream>>>(Wk, 1024, 0, Akh, Akl, 1024, dtflag);
    tsplit_k<<<dim3(16, 16), 256, 0, stream>>>(Wv, 1024, 0, Avh, Avl, 1024, dtflag);
    tsplit_k<<<dim3(16, 16), 256, 0, stream>>>(Wo, 1024, 0, Both, Botl, 1024, dtflag);
    split_x_k<<<8192, 256, 0, stream>>>(inputs, Xh, Xl, dtflag);
    // weight-weight folds (MFMA): Wkq = Wk^T@Wq ; Wvo = Wv^T@Wo^T
    gemm_hilo_k<0><<<dim3(16, 16), 256, 0, stream>>>(Akh, Akl, 1024, Bqh, Bql, 1024,
                                                     Wkqh, Wkql, 1024, nullptr, 1.f);
    gemm_hilo_k<0><<<dim3(16, 16), 256, 0, stream>>>(Avh, Avl, 1024, Both, Botl, 1024,
                                                     Wvoh, Wvol, 1024, nullptr, 1.f);
    // enc-side folds (MFMA): KQb = (enc@Wkq + bkq)/32 ; Vob = enc@Wvo + bvo
    gemm_hilo_k<1><<<dim3(128, 16), 256, 0, stream>>>(Eh, El, 1024, Wkqh, Wkql, 1024,
                                                      KQb, nullptr, 0, bkq, 0.03125f);
    gemm_hilo_k<1><<<dim3(128, 16), 256, 0, stream>>>(Eh, El, 1024, Wvoh, Wvol, 1024,
                                                      Vob, nullptr, 0, bvo, 1.0f);
    skbq_k<<<2048, 256, 0, stream>>>(enc, ubq, cbqbk, skbqs, dtflag);
    // gate-weight frags (overwrite Eh/El region; enc GEMMs done)
    wfrag_k<<<256, 256, 0, stream>>>(Wih0, 1536, 0,    F0c, 32, dtflag);
    wfrag_k<<<256, 256, 0, stream>>>(Whh0, 1024, 0,    F0h, 32, dtflag);
    wfrag_k<<<256, 256, 0, stream>>>(Wih0, 1536, 1024, F0x, 16, dtflag);
    wfrag_k<<<256, 256, 0, stream>>>(Wih1, 1024, 0,    F1i, 32, dtflag);
    wfrag_k<<<256, 256, 0, stream>>>(Whh1, 1024, 0,    F1h, 32, dtflag);
    psc0_k<<<2048, 256, 0, stream>>>(c1f, KQb, psc);

    // ---- recurrent loop: 3 kernels/step ----
    for (int t = 0; t < kT; t++){
        int rd = (t & 1) * kB * kH;        // prev-state slot offset (u16 elems)
        int wr = ((t + 1) & 1) * kB * kH;  // new-state slot offset
        cv_k<<<256, 256, 0, stream>>>(psc, skbqs, maskflag, Vob, bof, Ch, Cl);
        gatecell_k<0><<<64, 512, 0, stream>>>(
            F0c, F0h, F0x, Ch, Cl, H0h + rd, H0l + rd,
            Xh + (size_t)t * 32 * kE, Xl + (size_t)t * 32 * kE,
            bias01, c0f, H0h + wr, H0l + wr, nullptr, t, nullptr, nullptr);
        gatecell_k<1><<<64, 512, 0, stream>>>(
            F1i, F1h, nullptr, H0h + wr, H0l + wr, H1h + rd, H1l + rd,
            nullptr, nullptr,
            bias1, c1f, H1h + wr, H1l + wr, out, t, KQb, psc);
    }
}

// Round 5
// 6741.052 us; speedup vs baseline: 2.3378x; 1.2610x over previous
//
#include <hip/hip_runtime.h>

typedef unsigned short u16;
typedef unsigned int   u32;
typedef unsigned char  u8;

constexpr int kB = 32, kT = 128, kS = 256, kE = 512, kH = 1024, kG = 4096;

typedef __attribute__((ext_vector_type(8))) short bfx8;
typedef __attribute__((ext_vector_type(4))) float fx4;

__device__ __forceinline__ float b2f(u16 v){ return __uint_as_float(((u32)v) << 16); }
__device__ __forceinline__ u16  f2b(float f){
    u32 u = __float_as_uint(f);
    return (u16)((u + 0x7FFFu + ((u >> 16) & 1u)) >> 16);
}
__device__ __forceinline__ float sigf(float x){ return 1.f / (1.f + expf(-x)); }
// dt==0: buffer is bf16 (u16); dt==1: buffer is fp32 (validated: fp32 on this harness)
__device__ __forceinline__ float ldin(const void* p, size_t i, int dt){
    return dt ? ((const float*)p)[i] : b2f(((const u16*)p)[i]);
}

// ---------------- input dtype detection (bf16 vs fp32) ----------------
__global__ void detect_dtype_k(const void* __restrict__ inputs, int* __restrict__ dtflag)
{
    __shared__ int bad;
    int t = threadIdx.x;
    if (t == 0) bad = 0;
    __syncthreads();
    const u16* p = (const u16*)inputs;
    int l = 0;
    for (int i = t; i < 4096; i += 256){
        u16 v = p[i];
        int e = (v >> 7) & 0xFF;
        if (v != 0 && (e < 90 || e > 140)) l = 1;
    }
    if (l) atomicOr(&bad, 1);
    __syncthreads();
    if (t == 0) *dtflag = bad;   // 1 = fp32, 0 = bf16
}

// ---------------- mask detection -> maskflag[b][s] = 1.0 (pad) / 0.0 ----------------
__global__ void prep_mask_k(const void* __restrict__ mask, float* __restrict__ maskflag)
{
    __shared__ int bad32, bad16, bad8, evenNZ;
    int t = threadIdx.x;
    if (t == 0){ bad32 = 0; bad16 = 0; bad8 = 0; evenNZ = 0; }
    __syncthreads();
    const u32* w32 = (const u32*)mask;
    const u16* w16 = (const u16*)mask;
    const u8*  w8  = (const u8*)mask;
    int l32 = 0, l16 = 0, l8 = 0, lev = 0;
    for (int i = t; i < 2048; i += 256){ u32 v = w32[i]; l32 |= (v > 1u); }
    for (int i = t; i < 4096; i += 256){
        u16 v = w16[i];
        l16 |= (v != 0 && v != 0x3F80u);
        if ((i & 1) == 0 && v != 0) lev = 1;
    }
    for (int i = t; i < 8192; i += 256){ l8 |= (w8[i] > 1); }
    if (l32) atomicOr(&bad32, 1);
    if (l16) atomicOr(&bad16, 1);
    if (l8)  atomicOr(&bad8, 1);
    if (lev) atomicOr(&evenNZ, 1);
    __syncthreads();
    int mode;                       // 0=int32, 1=bf16, 2=uint8, 3=fp32
    if (!bad32)       mode = 0;
    else if (!bad16)  mode = evenNZ ? 1 : 3;
    else if (!bad8)   mode = 2;
    else              mode = 3;
    for (int i = t; i < kB * kS; i += 256){
        bool m;
        if (mode == 0)      m = (((const int*)mask)[i] != 0);
        else if (mode == 1) m = (w16[i] != 0);
        else if (mode == 2) m = (w8[i] != 0);
        else                m = (((const float*)mask)[i] != 0.f);
        maskflag[i] = m ? 1.f : 0.f;
    }
}

// ---------------- bias / fold-vector precompute ----------------
__global__ void prep_bias_k(const void* __restrict__ Wq, const void* __restrict__ bq,
                            const void* __restrict__ Wk, const void* __restrict__ bk,
                            const void* __restrict__ bv, const void* __restrict__ Wo,
                            const void* __restrict__ bo,
                            const void* __restrict__ bih0, const void* __restrict__ bhh0,
                            const void* __restrict__ bih1, const void* __restrict__ bhh1,
                            float* __restrict__ bkq, float* __restrict__ bvo,
                            float* __restrict__ ubq, float* __restrict__ bof,
                            float* __restrict__ bias01, float* __restrict__ bias1,
                            float* __restrict__ cbqbk, const int* __restrict__ dtflag)
{
    int dt = *dtflag;
    int idx = blockIdx.x * 256 + threadIdx.x;
    if (idx < 1024){
        float s = 0.f;
        for (int i = 0; i < 1024; i++) s += ldin(bk, i, dt) * ldin(Wq, (size_t)i * 1024 + idx, dt);
        bkq[idx] = s;
    } else if (idx < 2048){ int o2 = idx - 1024;
        float s = 0.f;
        for (int h = 0; h < 1024; h++) s += ldin(bv, h, dt) * ldin(Wo, (size_t)o2 * 1024 + h, dt);
        bvo[o2] = s;
    } else if (idx < 3072){ int e = idx - 2048;
        float s = 0.f;
        for (int i = 0; i < 1024; i++) s += ldin(bq, i, dt) * ldin(Wk, (size_t)i * 1024 + e, dt);
        ubq[e] = s;
    } else if (idx < 4096){ int o2 = idx - 3072;
        bof[o2] = ldin(bo, o2, dt);
    } else if (idx < 8192){ int j = idx - 4096;
        bias01[j] = ldin(bih0, j, dt) + ldin(bhh0, j, dt);
    } else if (idx < 12288){ int j = idx - 8192;
        bias1[j] = ldin(bih1, j, dt) + ldin(bhh1, j, dt);
    } else if (idx == 12288){
        float s = 0.f;
        for (int i = 0; i < 1024; i++) s += ldin(bq, i, dt) * ldin(bk, i, dt);
        cbqbk[0] = s;
    }
}

// ---------------- initial states: c0,c1 from enc_c; zero h hi/lo buffers ----------------
__global__ void init_state_k(const void* __restrict__ enc_c,
                             float* __restrict__ c0, float* __restrict__ c1,
                             u16* __restrict__ H0h, u16* __restrict__ H0l,
                             u16* __restrict__ H1h, u16* __restrict__ H1l,
                             const int* __restrict__ dtflag)
{
    int dt = *dtflag;
    int idx = blockIdx.x * 256 + threadIdx.x;     // 32768
    int b = idx >> 10, h = idx & 1023;
    float cv = (h < 512) ? ldin(enc_c, (size_t)b * 512 + h, dt)
                         : ldin(enc_c, (size_t)(32 + b) * 512 + (h - 512), dt);
    c0[idx] = cv; c1[idx] = cv;
    H0h[idx] = 0; H0l[idx] = 0;
    H1h[idx] = 0; H1l[idx] = 0;
}

// ---------------- elementwise hi/lo bf16 split (same layout) ----------------
__global__ void split_plain_k(const void* __restrict__ src, u16* __restrict__ Oh,
                              u16* __restrict__ Ol, int n, const int* __restrict__ dtflag)
{
    int dt = *dtflag;
    int idx = blockIdx.x * 256 + threadIdx.x;
    if (idx >= n) return;
    float v = ldin(src, idx, dt);
    u16 h = f2b(v);
    Oh[idx] = h;
    Ol[idx] = f2b(v - b2f(h));
}

// ---------------- x split with (b,t)->m remap: X[(t*32+b)*512 + e] ----------------
__global__ void split_x_k(const void* __restrict__ inputs, u16* __restrict__ Xh,
                          u16* __restrict__ Xl, const int* __restrict__ dtflag)
{
    int dt = *dtflag;
    int idx = blockIdx.x * 256 + threadIdx.x;        // 2097152 = 32*128*512
    int b = idx >> 16, t = (idx >> 9) & 127, e = idx & 511;
    float v = ldin(inputs, idx, dt);
    u16 h = f2b(v);
    size_t o = ((size_t)(t * 32 + b) << 9) + e;
    Xh[o] = h;
    Xl[o] = f2b(v - b2f(h));
}

// ---------------- transpose + hi/lo split: O[c][r] = split(in[r][col_off + c]) ----------------
__global__ void tsplit_k(const void* __restrict__ W, int ldw, int col_off,
                         u16* __restrict__ Oh, u16* __restrict__ Ol, int ldo,
                         const int* __restrict__ dtflag)
{
    __shared__ float tile[64][65];
    int dt = *dtflag;
    int r0 = blockIdx.x * 64, c0 = blockIdx.y * 64;
    for (int i = 0; i < 16; i++){
        int idx = threadIdx.x + i * 256;
        int rr = idx >> 6, cc = idx & 63;
        tile[rr][cc] = ldin(W, (size_t)(r0 + rr) * ldw + col_off + c0 + cc, dt);
    }
    __syncthreads();
    for (int i = 0; i < 16; i++){
        int idx = threadIdx.x + i * 256;
        int cr = idx >> 6, rc = idx & 63;
        float v = tile[rc][cr];
        u16 h = f2b(v);
        size_t o = (size_t)(c0 + cr) * ldo + r0 + rc;
        Oh[o] = h;
        Ol[o] = f2b(v - b2f(h));
    }
}

// ---------------- weight frag reorder: F[ct][ks][lane][j], KSS k-slices ----------------
__global__ __launch_bounds__(256) void wfrag_k(const void* __restrict__ W, int ldw, int col_off,
                                               u16* __restrict__ F, int KSS,
                                               const int* __restrict__ dtflag)
{
    int dt = *dtflag;
    int ct = blockIdx.x;                 // 0..255 (16 output cols each)
    int iters = KSS * 2;                 // KSS*512 / 256
    for (int i = 0; i < iters; i++){
        int flat = threadIdx.x + i * 256;
        int ks = flat >> 9, r = flat & 511, l = r >> 3, j = r & 7;
        int row = ct * 16 + (l & 15);
        int k = ks * 32 + (l >> 4) * 8 + j;
        F[(size_t)ct * (KSS * 512) + flat] = f2b(ldin(W, (size_t)row * ldw + col_off + k, dt));
    }
}

// ---------------- generic hi/lo MFMA GEMM: Out[m][n] = sum_k A[m][k]*B[k][n], K=1024 ----------------
template<int EPI>
__global__ __launch_bounds__(256) void gemm_hilo_k(
    const u16* __restrict__ Ah, const u16* __restrict__ Al, int ldA,
    const u16* __restrict__ Bh, const u16* __restrict__ Bl, int ldB,
    u16* __restrict__ OutH, u16* __restrict__ OutL, int ldO,
    const float* __restrict__ bias, float scale)
{
    __shared__ __align__(16) u16 Bsh[64][40];
    __shared__ __align__(16) u16 Bsl[64][40];
    int tid = threadIdx.x, wave = tid >> 6, lane = tid & 63;
    int m0 = blockIdx.x * 64, n0 = blockIdx.y * 64;
    int rA = lane & 15, kq = lane >> 4;
    fx4 acc[4];
    #pragma unroll
    for (int nt = 0; nt < 4; nt++) acc[nt] = (fx4){0.f, 0.f, 0.f, 0.f};
    int skk = tid >> 3, snn = (tid & 7) * 8;
    for (int k0 = 0; k0 < 1024; k0 += 32){
        bfx8 vh = *(const bfx8*)(Bh + (size_t)(k0 + skk) * ldB + n0 + snn);
        bfx8 vl = *(const bfx8*)(Bl + (size_t)(k0 + skk) * ldB + n0 + snn);
        __syncthreads();
        #pragma unroll
        for (int q = 0; q < 8; q++){ Bsh[snn + q][skk] = (u16)vh[q]; Bsl[snn + q][skk] = (u16)vl[q]; }
        __syncthreads();
        size_t abase = (size_t)(m0 + wave * 16 + rA) * ldA + k0 + kq * 8;
        bfx8 a_h = *(const bfx8*)(Ah + abase);
        bfx8 a_l = *(const bfx8*)(Al + abase);
        #pragma unroll
        for (int nt = 0; nt < 4; nt++){
            bfx8 b_h = *(const bfx8*)&Bsh[nt * 16 + rA][kq * 8];
            bfx8 b_l = *(const bfx8*)&Bsl[nt * 16 + rA][kq * 8];
            acc[nt] = __builtin_amdgcn_mfma_f32_16x16x32_bf16(a_h, b_h, acc[nt], 0, 0, 0);
            acc[nt] = __builtin_amdgcn_mfma_f32_16x16x32_bf16(a_h, b_l, acc[nt], 0, 0, 0);
            acc[nt] = __builtin_amdgcn_mfma_f32_16x16x32_bf16(a_l, b_h, acc[nt], 0, 0, 0);
        }
    }
    #pragma unroll
    for (int nt = 0; nt < 4; nt++){
        #pragma unroll
        for (int i = 0; i < 4; i++){
            int m = m0 + wave * 16 + kq * 4 + i;
            int n = n0 + nt * 16 + rA;
            float v = acc[nt][i];
            if (EPI == 0){
                u16 h = f2b(v);
                OutH[(size_t)m * ldO + n] = h;
                OutL[(size_t)m * ldO + n] = f2b(v - b2f(h));
            } else {
                float v2 = (v + bias[n]) * scale;
                OutH[(((size_t)(((m & 31) << 8) | (m >> 5))) << 10) + n] = f2b(v2);
            }
        }
    }
}

// ---------------- skbqs[b][s] = (bq.K[s,b,:]) * scale ----------------
__global__ __launch_bounds__(256) void skbq_k(
    const void* __restrict__ enc, const float* __restrict__ ubq,
    const float* __restrict__ cbqbk, float* __restrict__ skbqs,
    const int* __restrict__ dtflag)
{
    int dt = *dtflag;
    int w = (blockIdx.x * 256 + threadIdx.x) >> 6;   // 0..8191 = s*32+b
    int lane = threadIdx.x & 63;
    int s = w >> 5, b = w & 31;
    size_t base = (size_t)w * 1024 + lane * 16;
    float acc = 0.f;
    #pragma unroll
    for (int i = 0; i < 16; i++) acc += ubq[lane * 16 + i] * ldin(enc, base + i, dt);
    #pragma unroll
    for (int off = 32; off; off >>= 1) acc += __shfl_down(acc, off, 64);
    if (lane == 0) skbqs[b * 256 + s] = (acc + cbqbk[0]) * 0.03125f;
}

// ---------------- gates MFMA partial: grid (64 ht, 4 q), 256 thr (4 waves) ----------------
// LAYER 0: slices ctx(0-31), h0(32-63), x(64-79); per block 20 (5/wave).
// LAYER 1: slices h0new(0-31), h1(32-63); per block 16 (4/wave).
// pp[q][b][gate*1024 + ht*16 + hl] partial over this block's K-range.
template<int LAYER>
__global__ __launch_bounds__(256) void gmm_k(
    const u16* __restrict__ f0, const u16* __restrict__ f1, const u16* __restrict__ f2,
    const u16* __restrict__ a0h, const u16* __restrict__ a0l,
    const u16* __restrict__ a1h, const u16* __restrict__ a1l,
    const u16* __restrict__ a2h, const u16* __restrict__ a2l,
    float* __restrict__ pp)
{
    __shared__ float red[4][32][64];
    int ht = blockIdx.x, q = blockIdx.y;
    int tid = threadIdx.x, wave = tid >> 6, lane = tid & 63;
    int rA = lane & 15, kq = lane >> 4;
    constexpr int PER_W = (LAYER == 0) ? 5 : 4;
    fx4 acc[2][4];
    #pragma unroll
    for (int mt = 0; mt < 2; mt++)
        #pragma unroll
        for (int nt = 0; nt < 4; nt++) acc[mt][nt] = (fx4){0.f, 0.f, 0.f, 0.f};

    #pragma unroll
    for (int si = 0; si < PER_W; si++){
        int s = q * (PER_W * 4) + wave * PER_W + si;
        const u16 *F, *ah, *al; int ks, ld, KSSF;
        if (LAYER == 0){
            if (s < 32)      { F = f0; ks = s;      ah = a0h; al = a0l; ld = 1024; KSSF = 32; }
            else if (s < 64) { F = f1; ks = s - 32; ah = a1h; al = a1l; ld = 1024; KSSF = 32; }
            else             { F = f2; ks = s - 64; ah = a2h; al = a2l; ld = 512;  KSSF = 16; }
        } else {
            if (s < 32)      { F = f0; ks = s;      ah = a0h; al = a0l; }
            else             { F = f1; ks = s - 32; ah = a1h; al = a1l; }
            ld = 1024; KSSF = 32;
        }
        int koff = ks * 32 + kq * 8;
        bfx8 a_h0 = *(const bfx8*)(ah + (size_t)rA * ld + koff);
        bfx8 a_l0 = *(const bfx8*)(al + (size_t)rA * ld + koff);
        bfx8 a_h1 = *(const bfx8*)(ah + (size_t)(16 + rA) * ld + koff);
        bfx8 a_l1 = *(const bfx8*)(al + (size_t)(16 + rA) * ld + koff);
        #pragma unroll
        for (int nt = 0; nt < 4; nt++){
            bfx8 bf = *(const bfx8*)(F + ((size_t)((nt * 64 + ht) * KSSF + ks) * 64 + lane) * 8);
            acc[0][nt] = __builtin_amdgcn_mfma_f32_16x16x32_bf16(a_h0, bf, acc[0][nt], 0, 0, 0);
            acc[0][nt] = __builtin_amdgcn_mfma_f32_16x16x32_bf16(a_l0, bf, acc[0][nt], 0, 0, 0);
            acc[1][nt] = __builtin_amdgcn_mfma_f32_16x16x32_bf16(a_h1, bf, acc[1][nt], 0, 0, 0);
            acc[1][nt] = __builtin_amdgcn_mfma_f32_16x16x32_bf16(a_l1, bf, acc[1][nt], 0, 0, 0);
        }
    }
    // C/D layout: col = lane&15 (rA), row = kq*4 + i; rows are b (mt*16 +)
    #pragma unroll
    for (int mt = 0; mt < 2; mt++)
        #pragma unroll
        for (int nt = 0; nt < 4; nt++)
            #pragma unroll
            for (int i = 0; i < 4; i++)
                red[wave][mt * 16 + kq * 4 + i][nt * 16 + rA] = acc[mt][nt][i];
    __syncthreads();
    #pragma unroll
    for (int i = 0; i < 8; i++){
        int flat = tid + i * 256;             // 0..2047
        int b = flat >> 6, cl = flat & 63;
        int nt = cl >> 4, hl = cl & 15;
        float v = (red[0][b][cl] + red[1][b][cl]) + (red[2][b][cl] + red[3][b][cl]);
        pp[(((size_t)(q * 32 + b)) << 12) + nt * 1024 + ht * 16 + hl] = v;
    }
}

// ---------------- layer-0 cell: g = sum_q pp + bias; update c0, h0 hi/lo ----------------
__global__ __launch_bounds__(256) void cell0_k(
    const float* __restrict__ pp, const float* __restrict__ biasv,
    float* __restrict__ c_state, u16* __restrict__ outHh, u16* __restrict__ outHl)
{
    int idx = blockIdx.x * 256 + threadIdx.x;     // 32768
    int b = idx >> 10, h = idx & 1023;
    float g[4];
    #pragma unroll
    for (int gate = 0; gate < 4; gate++){
        int j = gate * 1024 + h;
        g[gate] = biasv[j]
                + pp[(((size_t)(0 * 32 + b)) << 12) + j]
                + pp[(((size_t)(1 * 32 + b)) << 12) + j]
                + pp[(((size_t)(2 * 32 + b)) << 12) + j]
                + pp[(((size_t)(3 * 32 + b)) << 12) + j];
    }
    float gi_ = sigf(g[0]);
    float gf_ = sigf(g[1]);
    float gg_ = tanhf(g[2]);
    float go_ = sigf(g[3]);
    float c = gf_ * c_state[idx] + gi_ * gg_;
    c_state[idx] = c;
    float hv = go_ * tanhf(c);
    u16 hh = f2b(hv);
    outHh[idx] = hh;
    outHl[idx] = f2b(hv - b2f(hh));
}

// ---------------- fused: cell1(t-1) + scores + softmax + ctx(t) ----------------
// 32 blocks (b) x 1024 threads. t in [0,128]: cell part if t>0, attn part if t<128.
__global__ __launch_bounds__(1024) void fused_attn_k(
    const float* __restrict__ pp, const float* __restrict__ bias1,
    float* __restrict__ c1f, u16* __restrict__ H1h, u16* __restrict__ H1l,
    float* __restrict__ y_out, int t,
    const u16* __restrict__ KQb, const u16* __restrict__ Vob,
    const float* __restrict__ skbqs, const float* __restrict__ maskflag,
    const float* __restrict__ bof, u16* __restrict__ Ch, u16* __restrict__ Cl)
{
    __shared__ float cs[1024];
    __shared__ float sred[256][4];
    __shared__ float attn[256];
    __shared__ float wred[8];
    __shared__ float2 cpart[2][512];
    int b = blockIdx.x, tid = threadIdx.x;
    float c;
    int cidx = (b << 10) + tid;
    if (t > 0){
        float g[4];
        #pragma unroll
        for (int gate = 0; gate < 4; gate++){
            int j = gate * 1024 + tid;
            g[gate] = bias1[j]
                    + pp[(((size_t)(0 * 32 + b)) << 12) + j]
                    + pp[(((size_t)(1 * 32 + b)) << 12) + j]
                    + pp[(((size_t)(2 * 32 + b)) << 12) + j]
                    + pp[(((size_t)(3 * 32 + b)) << 12) + j];
        }
        float gi_ = sigf(g[0]);
        float gf_ = sigf(g[1]);
        float gg_ = tanhf(g[2]);
        float go_ = sigf(g[3]);
        c = gf_ * c1f[cidx] + gi_ * gg_;
        c1f[cidx] = c;
        float hv = go_ * tanhf(c);
        u16 hh = f2b(hv);
        H1h[cidx] = hh;
        H1l[cidx] = f2b(hv - b2f(hh));
        y_out[(((size_t)b * kT + (t - 1)) << 10) + tid] = hv;
    } else {
        c = c1f[cidx];
    }
    cs[tid] = c;
    __syncthreads();
    if (t == 128) return;
    // ---- scores: thread (s = tid>>2, qd = tid&3): dot over h-quarter ----
    {
        int s = tid >> 2, qd = tid & 3;
        const u16* kp = KQb + (((size_t)((b << 8) | s)) << 10) + qd * 256;
        const float* cc = &cs[qd * 256];
        float a = 0.f;
        #pragma unroll 8
        for (int i = 0; i < 256; i += 8){
            uint4 kv = *(const uint4*)(kp + i);
            a += cc[i]     * b2f((u16)(kv.x & 0xFFFFu)) + cc[i + 1] * b2f((u16)(kv.x >> 16));
            a += cc[i + 2] * b2f((u16)(kv.y & 0xFFFFu)) + cc[i + 3] * b2f((u16)(kv.y >> 16));
            a += cc[i + 4] * b2f((u16)(kv.z & 0xFFFFu)) + cc[i + 5] * b2f((u16)(kv.z >> 16));
            a += cc[i + 6] * b2f((u16)(kv.w & 0xFFFFu)) + cc[i + 7] * b2f((u16)(kv.w >> 16));
        }
        sred[s][qd] = a;
    }
    __syncthreads();
    if (tid < 256){
        float sc = (sred[tid][0] + sred[tid][1]) + (sred[tid][2] + sred[tid][3]);
        int is = (b << 8) + tid;
        sc = (maskflag[is] != 0.f) ? -1e9f : sc + skbqs[is];
        attn[tid] = sc;
        float m = sc;
        #pragma unroll
        for (int off = 32; off; off >>= 1) m = fmaxf(m, __shfl_down(m, off, 64));
        if ((tid & 63) == 0) wred[tid >> 6] = m;
    }
    __syncthreads();
    if (tid < 256){
        float mm = fmaxf(fmaxf(wred[0], wred[1]), fmaxf(wred[2], wred[3]));
        float ex = expf(attn[tid] - mm);
        float ssum = ex;
        #pragma unroll
        for (int off = 32; off; off >>= 1) ssum += __shfl_down(ssum, off, 64);
        if ((tid & 63) == 0) wred[4 + (tid >> 6)] = ssum;
        sred[tid][0] = ex;
    }
    __syncthreads();
    if (tid < 256){
        float tot = (wred[4] + wred[5]) + (wred[6] + wred[7]);
        attn[tid] = sred[tid][0] / tot;
    }
    __syncthreads();
    // ---- ctx: thread (sh = tid>>9, hp = tid&511): 2 h, 128 s ----
    {
        int sh = tid >> 9, hp = tid & 511;
        const u16* vcol = Vob + ((size_t)b << 18) + hp * 2;
        float a0 = 0.f, a1 = 0.f;
        int s0 = sh * 128;
        #pragma unroll 8
        for (int s = s0; s < s0 + 128; s++){
            u32 v = *(const u32*)(vcol + ((size_t)s << 10));
            float at = attn[s];
            a0 += at * b2f((u16)(v & 0xFFFFu));
            a1 += at * b2f((u16)(v >> 16));
        }
        cpart[sh][hp] = make_float2(a0, a1);
    }
    __syncthreads();
    if (tid < 512){
        float2 p0 = cpart[0][tid], p1 = cpart[1][tid];
        int h = tid * 2;
        float v0 = p0.x + p1.x + bof[h];
        float v1 = p0.y + p1.y + bof[h + 1];
        u16 h0 = f2b(v0), h1 = f2b(v1);
        int base = (b << 10) + h;
        Ch[base] = h0;     Ch[base + 1] = h1;
        Cl[base] = f2b(v0 - b2f(h0));
        Cl[base + 1] = f2b(v1 - b2f(h1));
    }
}

extern "C" void kernel_launch(void* const* d_in, const int* in_sizes, int n_in,
                              void* d_out, int out_size, void* d_ws, size_t ws_size,
                              hipStream_t stream)
{
    const void* inputs = d_in[0];
    const void* enc    = d_in[1];
    const void* enc_c  = d_in[2];
    const void* mask   = d_in[3];
    const void* Wq   = d_in[4];
    const void* bq   = d_in[5];
    const void* Wk   = d_in[6];
    const void* bk   = d_in[7];
    const void* Wv   = d_in[8];
    const void* bv   = d_in[9];
    const void* Wo   = d_in[10];
    const void* bo   = d_in[11];
    const void* Wih0 = d_in[12];
    const void* Whh0 = d_in[13];
    const void* bih0 = d_in[14];
    const void* bhh0 = d_in[15];
    const void* Wih1 = d_in[16];
    const void* Whh1 = d_in[17];
    const void* bih1 = d_in[18];
    const void* bhh1 = d_in[19];
    float* out = (float*)d_out;
    (void)in_sizes; (void)n_in; (void)out_size; (void)ws_size;

    char* ws = (char*)d_ws;
    size_t off = 0;
    auto alloc = [&](size_t bytes) -> void* {
        void* p = ws + off; off += (bytes + 255) & ~(size_t)255; return p;
    };
    // POOL_A (37.75MB): Eh/El (split enc, dead after enc GEMMs)  ||  F0c,F0h,F1i,F1h,F0x (wfrag, loop)
    char* poolA = (char*)alloc((size_t)37748736);
    u16* Eh  = (u16*)poolA;                              // 16.8MB
    u16* El  = (u16*)(poolA + 16777216);
    u16* F0c = (u16*)poolA;                              // 8.4MB each
    u16* F0h = (u16*)(poolA + 8388608);
    u16* F1i = (u16*)(poolA + 16777216);
    u16* F1h = (u16*)(poolA + 25165824);
    u16* F0x = (u16*)(poolA + 33554432);                 // 4.2MB
    // POOL_B (16.8MB): ww-GEMM operand splits (dead after ww GEMMs)
    char* poolB = (char*)alloc((size_t)16777216);
    u16* Akh  = (u16*)poolB;
    u16* Akl  = (u16*)(poolB + 2097152);
    u16* Bqh  = (u16*)(poolB + 4194304);
    u16* Bql  = (u16*)(poolB + 6291456);
    u16* Avh  = (u16*)(poolB + 8388608);
    u16* Avl  = (u16*)(poolB + 10485760);
    u16* Both = (u16*)(poolB + 12582912);
    u16* Botl = (u16*)(poolB + 14680064);
    u16*  KQb  = (u16*)alloc((size_t)kB * kS * kH * 2);    // [b][s][o] (scale 1/32 folded)
    u16*  Vob  = (u16*)alloc((size_t)kB * kS * kH * 2);    // [b][s][o2] (incl. bvo)
    u16*  Xh   = (u16*)alloc((size_t)kB * kT * kE * 2);    // [t*32+b][e]
    u16*  Xl   = (u16*)alloc((size_t)kB * kT * kE * 2);
    u16*  Wkqh = (u16*)alloc((size_t)kH * kH * 2);
    u16*  Wkql = (u16*)alloc((size_t)kH * kH * 2);
    u16*  Wvoh = (u16*)alloc((size_t)kH * kH * 2);
    u16*  Wvol = (u16*)alloc((size_t)kH * kH * 2);
    float* pp  = (float*)alloc((size_t)4 * kB * kG * 4);   // [4][32][4096] partials (shared L0/L1)
    u16*  Ch   = (u16*)alloc((size_t)kB * kH * 2);
    u16*  Cl   = (u16*)alloc((size_t)kB * kH * 2);
    u16*  H0h  = (u16*)alloc((size_t)kB * kH * 2);
    u16*  H0l  = (u16*)alloc((size_t)kB * kH * 2);
    u16*  H1h  = (u16*)alloc((size_t)kB * kH * 2);
    u16*  H1l  = (u16*)alloc((size_t)kB * kH * 2);
    float* c0f = (float*)alloc(kB * kH * 4);
    float* c1f = (float*)alloc(kB * kH * 4);
    float* bkq = (float*)alloc(1024 * 4);
    float* bvo = (float*)alloc(1024 * 4);
    float* ubq = (float*)alloc(1024 * 4);
    float* bof = (float*)alloc(1024 * 4);
    float* bias01 = (float*)alloc(4096 * 4);
    float* bias1  = (float*)alloc(4096 * 4);
    float* cbqbk  = (float*)alloc(256);
    float* skbqs  = (float*)alloc(kB * kS * 4);
    float* maskflag = (float*)alloc(kB * kS * 4);
    int*   dtflag = (int*)alloc(256);

    // ---- one-time precompute ----
    detect_dtype_k<<<1, 256, 0, stream>>>(inputs, dtflag);
    prep_mask_k<<<1, 256, 0, stream>>>(mask, maskflag);
    prep_bias_k<<<49, 256, 0, stream>>>(Wq, bq, Wk, bk, bv, Wo, bo,
                                        bih0, bhh0, bih1, bhh1,
                                        bkq, bvo, ubq, bof, bias01, bias1, cbqbk, dtflag);
    init_state_k<<<128, 256, 0, stream>>>(enc_c, c0f, c1f, H0h, H0l, H1h, H1l, dtflag);
    split_plain_k<<<32768, 256, 0, stream>>>(enc, Eh, El, 8388608, dtflag);
    split_plain_k<<<4096, 256, 0, stream>>>(Wq, Bqh, Bql, 1048576, dtflag);
    tsplit_k<<<dim3(16, 16), 256, 0, stream>>>(Wk, 1024, 0, Akh, Akl, 1024, dtflag);
    tsplit_k<<<dim3(16, 16), 256, 0, stream>>>(Wv, 1024, 0, Avh, Avl, 1024, dtflag);
    tsplit_k<<<dim3(16, 16), 256, 0, stream>>>(Wo, 1024, 0, Both, Botl, 1024, dtflag);
    split_x_k<<<8192, 256, 0, stream>>>(inputs, Xh, Xl, dtflag);
    gemm_hilo_k<0><<<dim3(16, 16), 256, 0, stream>>>(Akh, Akl, 1024, Bqh, Bql, 1024,
                                                     Wkqh, Wkql, 1024, nullptr, 1.f);
    gemm_hilo_k<0><<<dim3(16, 16), 256, 0, stream>>>(Avh, Avl, 1024, Both, Botl, 1024,
                                                     Wvoh, Wvol, 1024, nullptr, 1.f);
    gemm_hilo_k<1><<<dim3(128, 16), 256, 0, stream>>>(Eh, El, 1024, Wkqh, Wkql, 1024,
                                                      KQb, nullptr, 0, bkq, 0.03125f);
    gemm_hilo_k<1><<<dim3(128, 16), 256, 0, stream>>>(Eh, El, 1024, Wvoh, Wvol, 1024,
                                                      Vob, nullptr, 0, bvo, 1.0f);
    skbq_k<<<2048, 256, 0, stream>>>(enc, ubq, cbqbk, skbqs, dtflag);
    wfrag_k<<<256, 256, 0, stream>>>(Wih0, 1536, 0,    F0c, 32, dtflag);
    wfrag_k<<<256, 256, 0, stream>>>(Whh0, 1024, 0,    F0h, 32, dtflag);
    wfrag_k<<<256, 256, 0, stream>>>(Wih0, 1536, 1024, F0x, 16, dtflag);
    wfrag_k<<<256, 256, 0, stream>>>(Wih1, 1024, 0,    F1i, 32, dtflag);
    wfrag_k<<<256, 256, 0, stream>>>(Whh1, 1024, 0,    F1h, 32, dtflag);

    // ---- recurrent loop: 4 kernels/step ----
    for (int t = 0; t < kT; t++){
        fused_attn_k<<<32, 1024, 0, stream>>>(pp, bias1, c1f, H1h, H1l, out, t,
                                              KQb, Vob, skbqs, maskflag, bof, Ch, Cl);
        gmm_k<0><<<dim3(64, 4), 256, 0, stream>>>(
            F0c, F0h, F0x, Ch, Cl, H0h, H0l,
            Xh + (size_t)t * 32 * kE, Xl + (size_t)t * 32 * kE, pp);
        cell0_k<<<128, 256, 0, stream>>>(pp, bias01, c0f, H0h, H0l);
        gmm_k<1><<<dim3(64, 4), 256, 0, stream>>>(
            F1i, F1h, nullptr, H0h, H0l, H1h, H1l, nullptr, nullptr, pp);
    }
    // epilogue: finish cell1 for t=127 (writes y[127]), skip attention
    fused_attn_k<<<32, 1024, 0, stream>>>(pp, bias1, c1f, H1h, H1l, out, 128,
                                          KQb, Vob, skbqs, maskflag, bof, Ch, Cl);
}